// Round 5
// baseline (718.683 us; speedup 1.0000x reference)
//
#include <hip/hip_runtime.h>
#include <math.h>

#define N_NODES 100000
#define N_EDGES 3200000
#define IN_CH   256
#define HID     64
#define OUTC    32
#define NB      ((N_NODES + 255) / 256)   // 391 (scan blocks, also node buckets)
#define NBUCK   ((N_NODES + 255) / 256)   // 391 buckets of 256 nodes (bucket = dst >> 8)
#define CHUNK   8192                      // edges per partition block
#define CAP     9216                      // bucket capacity: mean 8192, sigma ~90 -> +11 sigma

// ---------------- workspace layout (bytes) ----------------
static constexpr size_t align256(size_t x) { return (x + 255) & ~(size_t)255; }
static constexpr size_t OFF_DEG  = 0;                                          // N ints
static constexpr size_t OFF_PTR  = OFF_DEG  + align256((size_t)N_NODES * 4);   // N ints (exclusive)
static constexpr size_t OFF_BSUM = OFF_PTR  + align256((size_t)N_NODES * 4);   // 512 ints
static constexpr size_t OFF_GCUR = OFF_BSUM + align256(512 * 4);               // NBUCK ints
static constexpr size_t OFF_DIS  = OFF_GCUR + align256((size_t)NBUCK * 4);     // N floats
static constexpr size_t OFF_SRC  = OFF_DIS  + align256((size_t)N_NODES * 4);   // E ints
static constexpr size_t OFF_S1   = OFF_SRC  + align256((size_t)N_EDGES * 4);   // N*64 floats (s1 / s2)
static constexpr size_t OFF_H1   = OFF_S1   + (size_t)N_NODES * HID * 4;       // N*64 floats
// partition buffer (NBUCK*CAP ints = 14.4 MB) aliases the s1/h1 region (dead until gemm1)

// ---------------- bucket cursor init: gcur[b] = b*CAP ----------------
__global__ __launch_bounds__(256) void bucket_init(int* __restrict__ gcur) {
    int b = blockIdx.x * 256 + threadIdx.x;
    if (b < NBUCK) gcur[b] = b * CAP;
}

// ---------------- phase A: partition edges into coarse dst-buckets ----------------
// packed entry: src (17 bits) | dst_low8 << 17
__global__ __launch_bounds__(256) void partition_edges(const int* __restrict__ row,
                                                       const int* __restrict__ col,
                                                       int* __restrict__ gcur,
                                                       int* __restrict__ part) {
    __shared__ int lhist[NBUCK];
    __shared__ int lbase[NBUCK];
    __shared__ int lrank[NBUCK];
    const int t  = threadIdx.x;
    const int e0 = blockIdx.x * CHUNK;
    const int e1 = min(e0 + CHUNK, N_EDGES);
    for (int i = t; i < NBUCK; i += 256) { lhist[i] = 0; lrank[i] = 0; }
    __syncthreads();
    for (int e = e0 + t; e < e1; e += 256) {
        atomicAdd(&lhist[col[e] >> 8], 1);
    }
    __syncthreads();
    for (int i = t; i < NBUCK; i += 256) {
        int c = lhist[i];
        lbase[i] = (c > 0) ? atomicAdd(&gcur[i], c) : 0;
    }
    __syncthreads();
    for (int e = e0 + t; e < e1; e += 256) {
        int d = col[e];
        int b = d >> 8;
        int r = atomicAdd(&lrank[b], 1);
        part[lbase[b] + r] = row[e] | ((d & 255) << 17);
    }
}

// ---------------- phase B1: per-node degree from bucket data (dense writes) ----------
__global__ __launch_bounds__(256) void bucket_hist(const int* __restrict__ gcur,
                                                   const int* __restrict__ part,
                                                   int* __restrict__ deg) {
    __shared__ int lh[256];
    const int b = blockIdx.x;
    lh[threadIdx.x] = 0;
    __syncthreads();
    const int cnt = gcur[b] - b * CAP;
    for (int i = threadIdx.x; i < cnt; i += 256)
        atomicAdd(&lh[part[(size_t)b * CAP + i] >> 17], 1);
    __syncthreads();
    int v = b * 256 + threadIdx.x;
    if (v < N_NODES) deg[v] = lh[threadIdx.x];
}

__global__ __launch_bounds__(256) void compute_dis(const int* __restrict__ deg,
                                                   float* __restrict__ dis) {
    unsigned v = blockIdx.x * 256u + threadIdx.x;
    if (v < N_NODES) dis[v] = rsqrtf((float)deg[v] + 1.0f);  // +1 self-loop
}

// ---------------- 3-kernel exclusive scan of deg -> ptr ----------------
__global__ __launch_bounds__(256) void scan_block_sums(const int* __restrict__ deg,
                                                       int* __restrict__ bsum) {
    __shared__ int buf[256];
    unsigned i = blockIdx.x * 256u + threadIdx.x;
    int v = (i < N_NODES) ? deg[i] : 0;
    buf[threadIdx.x] = v;
    __syncthreads();
    for (int off = 128; off > 0; off >>= 1) {
        if (threadIdx.x < (unsigned)off) buf[threadIdx.x] += buf[threadIdx.x + off];
        __syncthreads();
    }
    if (threadIdx.x == 0) bsum[blockIdx.x] = buf[0];
}

__global__ __launch_bounds__(512) void scan_bsum(int* __restrict__ bsum) {
    __shared__ int buf[512];
    int t = threadIdx.x;
    int v = (t < NB) ? bsum[t] : 0;
    buf[t] = v;
    __syncthreads();
    for (int off = 1; off < 512; off <<= 1) {
        int add = (t >= off) ? buf[t - off] : 0;
        __syncthreads();
        buf[t] += add;
        __syncthreads();
    }
    if (t < NB) bsum[t] = buf[t] - v;  // exclusive
}

__global__ __launch_bounds__(256) void scan_block_scan(const int* __restrict__ deg,
                                                       const int* __restrict__ bsum,
                                                       int* __restrict__ ptr) {
    __shared__ int buf[256];
    unsigned i = blockIdx.x * 256u + threadIdx.x;
    int v = (i < N_NODES) ? deg[i] : 0;
    buf[threadIdx.x] = v;
    __syncthreads();
    for (int off = 1; off < 256; off <<= 1) {
        int add = (threadIdx.x >= (unsigned)off) ? buf[threadIdx.x - off] : 0;
        __syncthreads();
        buf[threadIdx.x] += add;
        __syncthreads();
    }
    if (i < N_NODES) ptr[i] = bsum[blockIdx.x] + buf[threadIdx.x] - v;  // exclusive
}

// ---------------- phase B2: fill srcs; writes confined to ~32KB window/block -------
__global__ __launch_bounds__(256) void bucket_fill(const int* __restrict__ gcur,
                                                   const int* __restrict__ part,
                                                   const int* __restrict__ ptr,
                                                   int* __restrict__ srcs) {
    __shared__ int lcur[256];
    const int b = blockIdx.x;
    lcur[threadIdx.x] = 0;
    __syncthreads();
    const int cnt = gcur[b] - b * CAP;
    for (int i = threadIdx.x; i < cnt; i += 256) {
        int p    = part[(size_t)b * CAP + i];
        int dlow = p >> 17;
        int src  = p & 0x1FFFF;
        int r    = atomicAdd(&lcur[dlow], 1);        // LDS cursor
        srcs[ptr[b * 256 + dlow] + r] = src;
    }
}

// ---------------- GEMM1: s1[n][j] = dis[n] * (x[n,:] @ W1[:,j]) ----------------
// k-tiled: W1 staged 64x64 (16 KB) at a time -> ~5 blocks/CU occupancy (vs 2 with
// the full 64 KB buffer). x rows via VMEM broadcast loads (global_load_dwordx4,
// fine-grained vmcnt scheduling) instead of all-or-nothing scalar lgkmcnt waits.
// block = 256 = 4 waves; 8 rows/wave; 32 rows/block; 3125 blocks exact.
__global__ __launch_bounds__(256) void gemm1(const float* __restrict__ x,
                                             const float* __restrict__ W1,
                                             const float* __restrict__ dis,
                                             float* __restrict__ s1) {
    __shared__ float wlds[64 * HID];  // 16 KB k-tile: [k_local][j]

    const int t = threadIdx.x;
    const int j = t & 63;
    const int g = t >> 6;  // NOT readfirstlane: keep x loads on the VMEM pipe
    const int rbase = blockIdx.x * 32 + g * 8;
    const float4* xr4 = (const float4*)(x + (size_t)rbase * IN_CH);  // row r at r*64 float4
    const float4* w4 = (const float4*)W1;

    float acc[8] = {0.f, 0.f, 0.f, 0.f, 0.f, 0.f, 0.f, 0.f};

    for (int kt = 0; kt < IN_CH / 64; ++kt) {  // 4 k-tiles of 64
        // stage W1 rows [kt*64, kt*64+64) -> LDS, coalesced float4
        {
            float4* l4 = (float4*)wlds;
#pragma unroll
            for (int i = 0; i < 4; ++i) l4[i * 256 + t] = w4[kt * 1024 + i * 256 + t];
        }
        __syncthreads();

#pragma unroll 4
        for (int k4 = 0; k4 < 16; ++k4) {
            float4 xv[8];
#pragma unroll
            for (int r = 0; r < 8; ++r) xv[r] = xr4[r * (IN_CH / 4) + kt * 16 + k4];
            const int kb = k4 * 4;
            float w0 = wlds[(kb + 0) * HID + j];
            float w1 = wlds[(kb + 1) * HID + j];
            float w2 = wlds[(kb + 2) * HID + j];
            float w3 = wlds[(kb + 3) * HID + j];
#pragma unroll
            for (int r = 0; r < 8; ++r)
                acc[r] += xv[r].x * w0 + xv[r].y * w1 + xv[r].z * w2 + xv[r].w * w3;
        }
        __syncthreads();  // before next tile overwrites wlds
    }

#pragma unroll
    for (int r = 0; r < 8; ++r) {
        s1[(size_t)(rbase + r) * HID + j] = dis[rbase + r] * acc[r];
    }
}

// ---------------- gather layer 1 + ELU ----------------
__global__ __launch_bounds__(256) void gather1(const float* __restrict__ s1,
                                               const int* __restrict__ ptr,
                                               const int* __restrict__ srcs,
                                               const float* __restrict__ dis,
                                               const float* __restrict__ b1,
                                               float* __restrict__ h1) {
    const int j = threadIdx.x & 63;
    const int v = __builtin_amdgcn_readfirstlane(blockIdx.x * 4 + (threadIdx.x >> 6));
    float acc = s1[(size_t)v * HID + j];              // self-loop term
    const int beg = ptr[v];
    const int end = (v + 1 < N_NODES) ? ptr[v + 1] : N_EDGES;
    int k = beg;
    for (; k + 8 <= end; k += 8) {
        int u0 = srcs[k],     u1 = srcs[k + 1], u2 = srcs[k + 2], u3 = srcs[k + 3];
        int u4 = srcs[k + 4], u5 = srcs[k + 5], u6 = srcs[k + 6], u7 = srcs[k + 7];
        float f0 = s1[(size_t)u0 * HID + j];
        float f1 = s1[(size_t)u1 * HID + j];
        float f2 = s1[(size_t)u2 * HID + j];
        float f3 = s1[(size_t)u3 * HID + j];
        float f4 = s1[(size_t)u4 * HID + j];
        float f5 = s1[(size_t)u5 * HID + j];
        float f6 = s1[(size_t)u6 * HID + j];
        float f7 = s1[(size_t)u7 * HID + j];
        acc += ((f0 + f1) + (f2 + f3)) + ((f4 + f5) + (f6 + f7));
    }
    for (; k < end; ++k) acc += s1[(size_t)srcs[k] * HID + j];
    float tt = dis[v] * acc + b1[j];
    h1[(size_t)v * HID + j] = tt > 0.f ? tt : (expf(tt) - 1.f);
}

// ---------------- GEMM2: s2[n][j] = dis[n] * (h1[n,:] @ W2[:,j]) ----------------
__global__ __launch_bounds__(256) void gemm2(const float* __restrict__ h,
                                             const float* __restrict__ W2,
                                             const float* __restrict__ dis,
                                             float* __restrict__ s2) {
    const int j  = threadIdx.x & 31;
    const int g  = threadIdx.x >> 5;
    const int n0 = blockIdx.x * 32 + g * 4;
    const float* h0 = h + (size_t)n0 * HID;
    float a0 = 0.f, a1 = 0.f, a2 = 0.f, a3 = 0.f;
#pragma unroll 4
    for (int k = 0; k < HID; ++k) {
        float w = W2[k * OUTC + j];
        a0 += h0[k] * w;
        a1 += h0[HID + k] * w;
        a2 += h0[2 * HID + k] * w;
        a3 += h0[3 * HID + k] * w;
    }
    size_t o = (size_t)n0 * OUTC + j;
    s2[o]            = dis[n0]     * a0;
    s2[o + OUTC]     = dis[n0 + 1] * a1;
    s2[o + 2 * OUTC] = dis[n0 + 2] * a2;
    s2[o + 3 * OUTC] = dis[n0 + 3] * a3;
}

// ---------------- gather layer 2 + ELU + final projection ----------------
__global__ __launch_bounds__(256) void gather2(const float* __restrict__ s2,
                                               const int* __restrict__ ptr,
                                               const int* __restrict__ srcs,
                                               const float* __restrict__ dis,
                                               const float* __restrict__ b2,
                                               const float* __restrict__ Wc,
                                               const float* __restrict__ bc,
                                               float* __restrict__ out) {
    const int j = threadIdx.x & 31;
    const int v = blockIdx.x * 8 + (threadIdx.x >> 5);
    float acc = s2[(size_t)v * OUTC + j];             // self-loop term
    const int beg = ptr[v];
    const int end = (v + 1 < N_NODES) ? ptr[v + 1] : N_EDGES;
    int k = beg;
    for (; k + 8 <= end; k += 8) {
        int u0 = srcs[k],     u1 = srcs[k + 1], u2 = srcs[k + 2], u3 = srcs[k + 3];
        int u4 = srcs[k + 4], u5 = srcs[k + 5], u6 = srcs[k + 6], u7 = srcs[k + 7];
        float f0 = s2[(size_t)u0 * OUTC + j];
        float f1 = s2[(size_t)u1 * OUTC + j];
        float f2 = s2[(size_t)u2 * OUTC + j];
        float f3 = s2[(size_t)u3 * OUTC + j];
        float f4 = s2[(size_t)u4 * OUTC + j];
        float f5 = s2[(size_t)u5 * OUTC + j];
        float f6 = s2[(size_t)u6 * OUTC + j];
        float f7 = s2[(size_t)u7 * OUTC + j];
        acc += ((f0 + f1) + (f2 + f3)) + ((f4 + f5) + (f6 + f7));
    }
    for (; k < end; ++k) acc += s2[(size_t)srcs[k] * OUTC + j];
    float t = dis[v] * acc + b2[j];
    float hh = t > 0.f ? t : (expf(t) - 1.f);
    float p = hh * Wc[j];
#pragma unroll
    for (int off = 16; off > 0; off >>= 1) p += __shfl_xor(p, off, 64);
    if (j == 0) out[v] = p + bc[0];
}

extern "C" void kernel_launch(void* const* d_in, const int* in_sizes, int n_in,
                              void* d_out, int out_size, void* d_ws, size_t ws_size,
                              hipStream_t stream) {
    const float* x  = (const float*)d_in[0];
    const int*   ei = (const int*)d_in[1];
    const float* W1 = (const float*)d_in[2];
    const float* b1 = (const float*)d_in[3];
    const float* W2 = (const float*)d_in[4];
    const float* b2 = (const float*)d_in[5];
    const float* Wc = (const float*)d_in[6];
    const float* bc = (const float*)d_in[7];
    float* out = (float*)d_out;

    const int* row = ei;            // edge_index[0] = source
    const int* col = ei + N_EDGES;  // edge_index[1] = target

    char* ws = (char*)d_ws;
    int*   deg  = (int*)  (ws + OFF_DEG);
    int*   ptr  = (int*)  (ws + OFF_PTR);
    int*   bsum = (int*)  (ws + OFF_BSUM);
    int*   gcur = (int*)  (ws + OFF_GCUR);
    float* dis  = (float*)(ws + OFF_DIS);
    int*   srcs = (int*)  (ws + OFF_SRC);
    float* s1   = (float*)(ws + OFF_S1);
    float* h1   = (float*)(ws + OFF_H1);
    float* s2   = (float*)(ws + OFF_S1);   // reuse (dead after gather1)
    int*   part = (int*)  (ws + OFF_S1);   // partition buffer aliases s1/h1 (dead before gemm1)

    bucket_init    <<<(NBUCK + 255) / 256, 256, 0, stream>>>(gcur);
    partition_edges<<<(N_EDGES + CHUNK - 1) / CHUNK, 256, 0, stream>>>(row, col, gcur, part);
    bucket_hist    <<<NBUCK, 256, 0, stream>>>(gcur, part, deg);
    compute_dis    <<<NB, 256, 0, stream>>>(deg, dis);
    scan_block_sums<<<NB, 256, 0, stream>>>(deg, bsum);
    scan_bsum      <<<1, 512, 0, stream>>>(bsum);
    scan_block_scan<<<NB, 256, 0, stream>>>(deg, bsum, ptr);
    bucket_fill    <<<NBUCK, 256, 0, stream>>>(gcur, part, ptr, srcs);

    gemm1  <<<N_NODES / 32, 256, 0, stream>>>(x, W1, dis, s1);
    gather1<<<N_NODES / 4, 256, 0, stream>>>(s1, ptr, srcs, dis, b1, h1);
    gemm2  <<<N_NODES / 32, 256, 0, stream>>>(h1, W2, dis, s2);
    gather2<<<N_NODES / 8, 256, 0, stream>>>(s2, ptr, srcs, dis, b2, Wc, bc, out);
}

// Round 6
// 610.057 us; speedup vs baseline: 1.1781x; 1.1781x over previous
//
#include <hip/hip_runtime.h>
#include <math.h>

#define N_NODES 100000
#define N_EDGES 3200000
#define IN_CH   256
#define HID     64
#define OUTC    32
#define NB      ((N_NODES + 255) / 256)   // 391 (scan blocks, also node buckets)
#define NBUCK   ((N_NODES + 255) / 256)   // 391 buckets of 256 nodes (bucket = dst >> 8)
#define CHUNK   8192                      // edges per partition block
#define CAP     9216                      // bucket capacity: mean 8192, sigma ~90 -> +11 sigma

// ---------------- workspace layout (bytes) ----------------
static constexpr size_t align256(size_t x) { return (x + 255) & ~(size_t)255; }
static constexpr size_t OFF_DEG  = 0;                                          // N ints
static constexpr size_t OFF_PTR  = OFF_DEG  + align256((size_t)N_NODES * 4);   // N ints (exclusive)
static constexpr size_t OFF_BSUM = OFF_PTR  + align256((size_t)N_NODES * 4);   // 512 ints
static constexpr size_t OFF_GCUR = OFF_BSUM + align256(512 * 4);               // NBUCK ints
static constexpr size_t OFF_DIS  = OFF_GCUR + align256((size_t)NBUCK * 4);     // N floats
static constexpr size_t OFF_SRC  = OFF_DIS  + align256((size_t)N_NODES * 4);   // E ints
static constexpr size_t OFF_S1   = OFF_SRC  + align256((size_t)N_EDGES * 4);   // N*64 floats (s1 / s2)
static constexpr size_t OFF_H1   = OFF_S1   + (size_t)N_NODES * HID * 4;       // N*64 floats
// partition buffer (NBUCK*CAP ints = 14.4 MB) aliases the s1/h1 region (dead until gemm1)

// ---------------- bucket cursor init: gcur[b] = b*CAP ----------------
__global__ __launch_bounds__(256) void bucket_init(int* __restrict__ gcur) {
    int b = blockIdx.x * 256 + threadIdx.x;
    if (b < NBUCK) gcur[b] = b * CAP;
}

// ---------------- phase A: partition edges into coarse dst-buckets ----------------
// packed entry: src (17 bits) | dst_low8 << 17
__global__ __launch_bounds__(256) void partition_edges(const int* __restrict__ row,
                                                       const int* __restrict__ col,
                                                       int* __restrict__ gcur,
                                                       int* __restrict__ part) {
    __shared__ int lhist[NBUCK];
    __shared__ int lbase[NBUCK];
    __shared__ int lrank[NBUCK];
    const int t  = threadIdx.x;
    const int e0 = blockIdx.x * CHUNK;
    const int e1 = min(e0 + CHUNK, N_EDGES);
    for (int i = t; i < NBUCK; i += 256) { lhist[i] = 0; lrank[i] = 0; }
    __syncthreads();
    for (int e = e0 + t; e < e1; e += 256) {
        atomicAdd(&lhist[col[e] >> 8], 1);
    }
    __syncthreads();
    for (int i = t; i < NBUCK; i += 256) {
        int c = lhist[i];
        lbase[i] = (c > 0) ? atomicAdd(&gcur[i], c) : 0;
    }
    __syncthreads();
    for (int e = e0 + t; e < e1; e += 256) {
        int d = col[e];
        int b = d >> 8;
        int r = atomicAdd(&lrank[b], 1);
        part[lbase[b] + r] = row[e] | ((d & 255) << 17);
    }
}

// ---------------- phase B1: per-node degree from bucket data (dense writes) ----------
__global__ __launch_bounds__(256) void bucket_hist(const int* __restrict__ gcur,
                                                   const int* __restrict__ part,
                                                   int* __restrict__ deg) {
    __shared__ int lh[256];
    const int b = blockIdx.x;
    lh[threadIdx.x] = 0;
    __syncthreads();
    const int cnt = gcur[b] - b * CAP;
    for (int i = threadIdx.x; i < cnt; i += 256)
        atomicAdd(&lh[part[(size_t)b * CAP + i] >> 17], 1);
    __syncthreads();
    int v = b * 256 + threadIdx.x;
    if (v < N_NODES) deg[v] = lh[threadIdx.x];
}

__global__ __launch_bounds__(256) void compute_dis(const int* __restrict__ deg,
                                                   float* __restrict__ dis) {
    unsigned v = blockIdx.x * 256u + threadIdx.x;
    if (v < N_NODES) dis[v] = rsqrtf((float)deg[v] + 1.0f);  // +1 self-loop
}

// ---------------- 3-kernel exclusive scan of deg -> ptr ----------------
__global__ __launch_bounds__(256) void scan_block_sums(const int* __restrict__ deg,
                                                       int* __restrict__ bsum) {
    __shared__ int buf[256];
    unsigned i = blockIdx.x * 256u + threadIdx.x;
    int v = (i < N_NODES) ? deg[i] : 0;
    buf[threadIdx.x] = v;
    __syncthreads();
    for (int off = 128; off > 0; off >>= 1) {
        if (threadIdx.x < (unsigned)off) buf[threadIdx.x] += buf[threadIdx.x + off];
        __syncthreads();
    }
    if (threadIdx.x == 0) bsum[blockIdx.x] = buf[0];
}

__global__ __launch_bounds__(512) void scan_bsum(int* __restrict__ bsum) {
    __shared__ int buf[512];
    int t = threadIdx.x;
    int v = (t < NB) ? bsum[t] : 0;
    buf[t] = v;
    __syncthreads();
    for (int off = 1; off < 512; off <<= 1) {
        int add = (t >= off) ? buf[t - off] : 0;
        __syncthreads();
        buf[t] += add;
        __syncthreads();
    }
    if (t < NB) bsum[t] = buf[t] - v;  // exclusive
}

__global__ __launch_bounds__(256) void scan_block_scan(const int* __restrict__ deg,
                                                       const int* __restrict__ bsum,
                                                       int* __restrict__ ptr) {
    __shared__ int buf[256];
    unsigned i = blockIdx.x * 256u + threadIdx.x;
    int v = (i < N_NODES) ? deg[i] : 0;
    buf[threadIdx.x] = v;
    __syncthreads();
    for (int off = 1; off < 256; off <<= 1) {
        int add = (threadIdx.x >= (unsigned)off) ? buf[threadIdx.x - off] : 0;
        __syncthreads();
        buf[threadIdx.x] += add;
        __syncthreads();
    }
    if (i < N_NODES) ptr[i] = bsum[blockIdx.x] + buf[threadIdx.x] - v;  // exclusive
}

// ---------------- phase B2: fill srcs; writes confined to ~32KB window/block -------
__global__ __launch_bounds__(256) void bucket_fill(const int* __restrict__ gcur,
                                                   const int* __restrict__ part,
                                                   const int* __restrict__ ptr,
                                                   int* __restrict__ srcs) {
    __shared__ int lcur[256];
    const int b = blockIdx.x;
    lcur[threadIdx.x] = 0;
    __syncthreads();
    const int cnt = gcur[b] - b * CAP;
    for (int i = threadIdx.x; i < cnt; i += 256) {
        int p    = part[(size_t)b * CAP + i];
        int dlow = p >> 17;
        int src  = p & 0x1FFFF;
        int r    = atomicAdd(&lcur[dlow], 1);        // LDS cursor
        srcs[ptr[b * 256 + dlow] + r] = src;
    }
}

// ---------------- GEMM1: s1[n][j] = dis[n] * (x[n,:] @ W1[:,j]) ----------------
// Round-4 scalar x-path (rows wave-uniform -> s_load_dwordx4, one 16B fetch per
// wave instead of 64 lane-addresses on VMEM) + round-5 16 KB k-tiled W1 LDS
// (occupancy ~5 waves/SIMD instead of 2 -> SMEM latency hidden across waves).
// Per k4-step: 32 v_fmac (64 cyc VALU) vs 8 s_load + 4 conflict-free ds_read.
// block = 256 = 4 waves; 8 rows/wave; 32 rows/block; 3125 blocks exact.
__global__ __launch_bounds__(256) void gemm1(const float* __restrict__ x,
                                             const float* __restrict__ W1,
                                             const float* __restrict__ dis,
                                             float* __restrict__ s1) {
    __shared__ float wlds[64 * HID];  // 16 KB k-tile: [k_local][j]

    const int t = threadIdx.x;
    const int j = t & 63;
    const int g = __builtin_amdgcn_readfirstlane(t >> 6);  // wave id: force SGPR path
    const int rbase = blockIdx.x * 32 + g * 8;
    const float4* xr4 = (const float4*)(x + (size_t)rbase * IN_CH);  // row r at r*64 float4
    const float4* w4 = (const float4*)W1;

    float acc[8] = {0.f, 0.f, 0.f, 0.f, 0.f, 0.f, 0.f, 0.f};

    for (int kt = 0; kt < IN_CH / 64; ++kt) {  // 4 k-tiles of 64
        // stage W1 rows [kt*64, kt*64+64) -> LDS, coalesced float4
        {
            float4* l4 = (float4*)wlds;
#pragma unroll
            for (int i = 0; i < 4; ++i) l4[i * 256 + t] = w4[kt * 1024 + i * 256 + t];
        }
        __syncthreads();

#pragma unroll 4
        for (int k4 = 0; k4 < 16; ++k4) {
            float4 xv[8];
#pragma unroll
            for (int r = 0; r < 8; ++r) xv[r] = xr4[r * (IN_CH / 4) + kt * 16 + k4];  // s_load
            const int kb = k4 * 4;
            float w0 = wlds[(kb + 0) * HID + j];
            float w1 = wlds[(kb + 1) * HID + j];
            float w2 = wlds[(kb + 2) * HID + j];
            float w3 = wlds[(kb + 3) * HID + j];
#pragma unroll
            for (int r = 0; r < 8; ++r)
                acc[r] += xv[r].x * w0 + xv[r].y * w1 + xv[r].z * w2 + xv[r].w * w3;
        }
        __syncthreads();  // before next tile overwrites wlds
    }

#pragma unroll
    for (int r = 0; r < 8; ++r) {
        s1[(size_t)(rbase + r) * HID + j] = dis[rbase + r] * acc[r];
    }
}

// ---------------- gather layer 1 + ELU ----------------
__global__ __launch_bounds__(256) void gather1(const float* __restrict__ s1,
                                               const int* __restrict__ ptr,
                                               const int* __restrict__ srcs,
                                               const float* __restrict__ dis,
                                               const float* __restrict__ b1,
                                               float* __restrict__ h1) {
    const int j = threadIdx.x & 63;
    const int v = __builtin_amdgcn_readfirstlane(blockIdx.x * 4 + (threadIdx.x >> 6));
    float acc = s1[(size_t)v * HID + j];              // self-loop term
    const int beg = ptr[v];
    const int end = (v + 1 < N_NODES) ? ptr[v + 1] : N_EDGES;
    int k = beg;
    for (; k + 8 <= end; k += 8) {
        int u0 = srcs[k],     u1 = srcs[k + 1], u2 = srcs[k + 2], u3 = srcs[k + 3];
        int u4 = srcs[k + 4], u5 = srcs[k + 5], u6 = srcs[k + 6], u7 = srcs[k + 7];
        float f0 = s1[(size_t)u0 * HID + j];
        float f1 = s1[(size_t)u1 * HID + j];
        float f2 = s1[(size_t)u2 * HID + j];
        float f3 = s1[(size_t)u3 * HID + j];
        float f4 = s1[(size_t)u4 * HID + j];
        float f5 = s1[(size_t)u5 * HID + j];
        float f6 = s1[(size_t)u6 * HID + j];
        float f7 = s1[(size_t)u7 * HID + j];
        acc += ((f0 + f1) + (f2 + f3)) + ((f4 + f5) + (f6 + f7));
    }
    for (; k < end; ++k) acc += s1[(size_t)srcs[k] * HID + j];
    float tt = dis[v] * acc + b1[j];
    h1[(size_t)v * HID + j] = tt > 0.f ? tt : (expf(tt) - 1.f);
}

// ---------------- GEMM2: s2[n][j] = dis[n] * (h1[n,:] @ W2[:,j]) ----------------
__global__ __launch_bounds__(256) void gemm2(const float* __restrict__ h,
                                             const float* __restrict__ W2,
                                             const float* __restrict__ dis,
                                             float* __restrict__ s2) {
    const int j  = threadIdx.x & 31;
    const int g  = threadIdx.x >> 5;
    const int n0 = blockIdx.x * 32 + g * 4;
    const float* h0 = h + (size_t)n0 * HID;
    float a0 = 0.f, a1 = 0.f, a2 = 0.f, a3 = 0.f;
#pragma unroll 4
    for (int k = 0; k < HID; ++k) {
        float w = W2[k * OUTC + j];
        a0 += h0[k] * w;
        a1 += h0[HID + k] * w;
        a2 += h0[2 * HID + k] * w;
        a3 += h0[3 * HID + k] * w;
    }
    size_t o = (size_t)n0 * OUTC + j;
    s2[o]            = dis[n0]     * a0;
    s2[o + OUTC]     = dis[n0 + 1] * a1;
    s2[o + 2 * OUTC] = dis[n0 + 2] * a2;
    s2[o + 3 * OUTC] = dis[n0 + 3] * a3;
}

// ---------------- gather layer 2 + ELU + final projection ----------------
__global__ __launch_bounds__(256) void gather2(const float* __restrict__ s2,
                                               const int* __restrict__ ptr,
                                               const int* __restrict__ srcs,
                                               const float* __restrict__ dis,
                                               const float* __restrict__ b2,
                                               const float* __restrict__ Wc,
                                               const float* __restrict__ bc,
                                               float* __restrict__ out) {
    const int j = threadIdx.x & 31;
    const int v = blockIdx.x * 8 + (threadIdx.x >> 5);
    float acc = s2[(size_t)v * OUTC + j];             // self-loop term
    const int beg = ptr[v];
    const int end = (v + 1 < N_NODES) ? ptr[v + 1] : N_EDGES;
    int k = beg;
    for (; k + 8 <= end; k += 8) {
        int u0 = srcs[k],     u1 = srcs[k + 1], u2 = srcs[k + 2], u3 = srcs[k + 3];
        int u4 = srcs[k + 4], u5 = srcs[k + 5], u6 = srcs[k + 6], u7 = srcs[k + 7];
        float f0 = s2[(size_t)u0 * OUTC + j];
        float f1 = s2[(size_t)u1 * OUTC + j];
        float f2 = s2[(size_t)u2 * OUTC + j];
        float f3 = s2[(size_t)u3 * OUTC + j];
        float f4 = s2[(size_t)u4 * OUTC + j];
        float f5 = s2[(size_t)u5 * OUTC + j];
        float f6 = s2[(size_t)u6 * OUTC + j];
        float f7 = s2[(size_t)u7 * OUTC + j];
        acc += ((f0 + f1) + (f2 + f3)) + ((f4 + f5) + (f6 + f7));
    }
    for (; k < end; ++k) acc += s2[(size_t)srcs[k] * OUTC + j];
    float t = dis[v] * acc + b2[j];
    float hh = t > 0.f ? t : (expf(t) - 1.f);
    float p = hh * Wc[j];
#pragma unroll
    for (int off = 16; off > 0; off >>= 1) p += __shfl_xor(p, off, 64);
    if (j == 0) out[v] = p + bc[0];
}

extern "C" void kernel_launch(void* const* d_in, const int* in_sizes, int n_in,
                              void* d_out, int out_size, void* d_ws, size_t ws_size,
                              hipStream_t stream) {
    const float* x  = (const float*)d_in[0];
    const int*   ei = (const int*)d_in[1];
    const float* W1 = (const float*)d_in[2];
    const float* b1 = (const float*)d_in[3];
    const float* W2 = (const float*)d_in[4];
    const float* b2 = (const float*)d_in[5];
    const float* Wc = (const float*)d_in[6];
    const float* bc = (const float*)d_in[7];
    float* out = (float*)d_out;

    const int* row = ei;            // edge_index[0] = source
    const int* col = ei + N_EDGES;  // edge_index[1] = target

    char* ws = (char*)d_ws;
    int*   deg  = (int*)  (ws + OFF_DEG);
    int*   ptr  = (int*)  (ws + OFF_PTR);
    int*   bsum = (int*)  (ws + OFF_BSUM);
    int*   gcur = (int*)  (ws + OFF_GCUR);
    float* dis  = (float*)(ws + OFF_DIS);
    int*   srcs = (int*)  (ws + OFF_SRC);
    float* s1   = (float*)(ws + OFF_S1);
    float* h1   = (float*)(ws + OFF_H1);
    float* s2   = (float*)(ws + OFF_S1);   // reuse (dead after gather1)
    int*   part = (int*)  (ws + OFF_S1);   // partition buffer aliases s1/h1 (dead before gemm1)

    bucket_init    <<<(NBUCK + 255) / 256, 256, 0, stream>>>(gcur);
    partition_edges<<<(N_EDGES + CHUNK - 1) / CHUNK, 256, 0, stream>>>(row, col, gcur, part);
    bucket_hist    <<<NBUCK, 256, 0, stream>>>(gcur, part, deg);
    compute_dis    <<<NB, 256, 0, stream>>>(deg, dis);
    scan_block_sums<<<NB, 256, 0, stream>>>(deg, bsum);
    scan_bsum      <<<1, 512, 0, stream>>>(bsum);
    scan_block_scan<<<NB, 256, 0, stream>>>(deg, bsum, ptr);
    bucket_fill    <<<NBUCK, 256, 0, stream>>>(gcur, part, ptr, srcs);

    gemm1  <<<N_NODES / 32, 256, 0, stream>>>(x, W1, dis, s1);
    gather1<<<N_NODES / 4, 256, 0, stream>>>(s1, ptr, srcs, dis, b1, h1);
    gemm2  <<<N_NODES / 32, 256, 0, stream>>>(h1, W2, dis, s2);
    gather2<<<N_NODES / 8, 256, 0, stream>>>(s2, ptr, srcs, dis, b2, Wc, bc, out);
}

// Round 8
// 535.187 us; speedup vs baseline: 1.3429x; 1.1399x over previous
//
#include <hip/hip_runtime.h>
#include <math.h>

#define N_NODES 100000
#define N_EDGES 3200000
#define IN_CH   256
#define HID     64
#define OUTC    32
#define NB      ((N_NODES + 255) / 256)   // 391 (scan blocks, also node buckets)
#define NBUCK   ((N_NODES + 255) / 256)   // 391 buckets of 256 nodes (bucket = dst >> 8)
#define CHUNK   8192                      // edges per partition block
#define CAP     9216                      // bucket capacity: mean 8192, sigma ~90 -> +11 sigma

// ---------------- workspace layout (bytes) ----------------
static constexpr size_t align256(size_t x) { return (x + 255) & ~(size_t)255; }
static constexpr size_t OFF_DEG  = 0;                                          // N ints
static constexpr size_t OFF_PTR  = OFF_DEG  + align256((size_t)N_NODES * 4);   // N ints (exclusive)
static constexpr size_t OFF_BSUM = OFF_PTR  + align256((size_t)N_NODES * 4);   // 512 ints
static constexpr size_t OFF_GCUR = OFF_BSUM + align256(512 * 4);               // NBUCK ints
static constexpr size_t OFF_DIS  = OFF_GCUR + align256((size_t)NBUCK * 4);     // N floats
static constexpr size_t OFF_SRC  = OFF_DIS  + align256((size_t)N_NODES * 4);   // E ints
static constexpr size_t OFF_S1   = OFF_SRC  + align256((size_t)N_EDGES * 4);   // N*64 floats (s1 / s2)
static constexpr size_t OFF_H1   = OFF_S1   + (size_t)N_NODES * HID * 4;       // N*64 floats
// partition buffer (NBUCK*CAP ints = 14.4 MB) aliases the s1/h1 region (dead until gemm1)

// ---------------- bucket cursor init: gcur[b] = b*CAP ----------------
__global__ __launch_bounds__(256) void bucket_init(int* __restrict__ gcur) {
    int b = blockIdx.x * 256 + threadIdx.x;
    if (b < NBUCK) gcur[b] = b * CAP;
}

// ---------------- phase A: partition edges into coarse dst-buckets ----------------
// packed entry: src (17 bits) | dst_low8 << 17
__global__ __launch_bounds__(256) void partition_edges(const int* __restrict__ row,
                                                       const int* __restrict__ col,
                                                       int* __restrict__ gcur,
                                                       int* __restrict__ part) {
    __shared__ int lhist[NBUCK];
    __shared__ int lbase[NBUCK];
    __shared__ int lrank[NBUCK];
    const int t  = threadIdx.x;
    const int e0 = blockIdx.x * CHUNK;
    const int e1 = min(e0 + CHUNK, N_EDGES);
    for (int i = t; i < NBUCK; i += 256) { lhist[i] = 0; lrank[i] = 0; }
    __syncthreads();
    for (int e = e0 + t; e < e1; e += 256) {
        atomicAdd(&lhist[col[e] >> 8], 1);
    }
    __syncthreads();
    for (int i = t; i < NBUCK; i += 256) {
        int c = lhist[i];
        lbase[i] = (c > 0) ? atomicAdd(&gcur[i], c) : 0;
    }
    __syncthreads();
    for (int e = e0 + t; e < e1; e += 256) {
        int d = col[e];
        int b = d >> 8;
        int r = atomicAdd(&lrank[b], 1);
        part[lbase[b] + r] = row[e] | ((d & 255) << 17);
    }
}

// ---------------- phase B1: per-node degree from bucket data (dense writes) ----------
__global__ __launch_bounds__(256) void bucket_hist(const int* __restrict__ gcur,
                                                   const int* __restrict__ part,
                                                   int* __restrict__ deg) {
    __shared__ int lh[256];
    const int b = blockIdx.x;
    lh[threadIdx.x] = 0;
    __syncthreads();
    const int cnt = gcur[b] - b * CAP;
    for (int i = threadIdx.x; i < cnt; i += 256)
        atomicAdd(&lh[part[(size_t)b * CAP + i] >> 17], 1);
    __syncthreads();
    int v = b * 256 + threadIdx.x;
    if (v < N_NODES) deg[v] = lh[threadIdx.x];
}

__global__ __launch_bounds__(256) void compute_dis(const int* __restrict__ deg,
                                                   float* __restrict__ dis) {
    unsigned v = blockIdx.x * 256u + threadIdx.x;
    if (v < N_NODES) dis[v] = rsqrtf((float)deg[v] + 1.0f);  // +1 self-loop
}

// ---------------- 3-kernel exclusive scan of deg -> ptr ----------------
__global__ __launch_bounds__(256) void scan_block_sums(const int* __restrict__ deg,
                                                       int* __restrict__ bsum) {
    __shared__ int buf[256];
    unsigned i = blockIdx.x * 256u + threadIdx.x;
    int v = (i < N_NODES) ? deg[i] : 0;
    buf[threadIdx.x] = v;
    __syncthreads();
    for (int off = 128; off > 0; off >>= 1) {
        if (threadIdx.x < (unsigned)off) buf[threadIdx.x] += buf[threadIdx.x + off];
        __syncthreads();
    }
    if (threadIdx.x == 0) bsum[blockIdx.x] = buf[0];
}

__global__ __launch_bounds__(512) void scan_bsum(int* __restrict__ bsum) {
    __shared__ int buf[512];
    int t = threadIdx.x;
    int v = (t < NB) ? bsum[t] : 0;
    buf[t] = v;
    __syncthreads();
    for (int off = 1; off < 512; off <<= 1) {
        int add = (t >= off) ? buf[t - off] : 0;
        __syncthreads();
        buf[t] += add;
        __syncthreads();
    }
    if (t < NB) bsum[t] = buf[t] - v;  // exclusive
}

__global__ __launch_bounds__(256) void scan_block_scan(const int* __restrict__ deg,
                                                       const int* __restrict__ bsum,
                                                       int* __restrict__ ptr) {
    __shared__ int buf[256];
    unsigned i = blockIdx.x * 256u + threadIdx.x;
    int v = (i < N_NODES) ? deg[i] : 0;
    buf[threadIdx.x] = v;
    __syncthreads();
    for (int off = 1; off < 256; off <<= 1) {
        int add = (threadIdx.x >= (unsigned)off) ? buf[threadIdx.x - off] : 0;
        __syncthreads();
        buf[threadIdx.x] += add;
        __syncthreads();
    }
    if (i < N_NODES) ptr[i] = bsum[blockIdx.x] + buf[threadIdx.x] - v;  // exclusive
}

// ---------------- phase B2: fill srcs; writes confined to ~32KB window/block -------
__global__ __launch_bounds__(256) void bucket_fill(const int* __restrict__ gcur,
                                                   const int* __restrict__ part,
                                                   const int* __restrict__ ptr,
                                                   int* __restrict__ srcs) {
    __shared__ int lcur[256];
    const int b = blockIdx.x;
    lcur[threadIdx.x] = 0;
    __syncthreads();
    const int cnt = gcur[b] - b * CAP;
    for (int i = threadIdx.x; i < cnt; i += 256) {
        int p    = part[(size_t)b * CAP + i];
        int dlow = p >> 17;
        int src  = p & 0x1FFFF;
        int r    = atomicAdd(&lcur[dlow], 1);        // LDS cursor
        srcs[ptr[b * 256 + dlow] + r] = src;
    }
}

// ---------------- GEMM1: s1[n][j] = dis[n] * (x[n,:] @ W1[:,j]) ----------------
// Register-blocked tile GEMM; operand streams on DIFFERENT wait counters:
// W1 k-chunks -> LDS (lgkmcnt only, fine-grained waits), x -> per-lane VMEM
// (vmcnt, fine-grained). 256 threads = 16x16, 4x4 fragment each; M-tile 64,
// N=64, K chunk 64. x row stride = IN_CH/4 = 64 float4s (r7 bug: was 16).
__global__ __launch_bounds__(256) void gemm1(const float* __restrict__ x,
                                             const float* __restrict__ W1,
                                             const float* __restrict__ dis,
                                             float* __restrict__ s1) {
    __shared__ float wlds[64 * HID];  // 16 KB k-chunk: [k_local][j]

    const int t  = threadIdx.x;
    const int tx = t & 15;   // col group: cols tx*4 .. tx*4+3
    const int ty = t >> 4;   // row group: rows ty*4 .. ty*4+3
    const int row0 = blockIdx.x * 64 + ty * 4;

    int r[4];
#pragma unroll
    for (int i = 0; i < 4; ++i) {
        int rr = row0 + i;
        r[i] = rr < N_NODES ? rr : N_NODES - 1;   // clamp (garbage compute, guarded store)
    }

    const float4* xb = (const float4*)x;          // row rr starts at rr*64 float4s
    float acc[4][4] = {{0.f}};

    for (int kt = 0; kt < IN_CH / 64; ++kt) {
        // stage W1 rows [kt*64, kt*64+64) -> LDS, coalesced float4
        {
            const float4* w4 = (const float4*)(W1 + (size_t)kt * 64 * HID);
            float4* l4 = (float4*)wlds;
#pragma unroll
            for (int i = 0; i < 4; ++i) l4[i * 256 + t] = w4[i * 256 + t];
        }
        __syncthreads();

        const float4* wl4 = (const float4*)wlds;
#pragma unroll 4
        for (int k4 = 0; k4 < 16; ++k4) {
            float4 xv[4];
#pragma unroll
            for (int i = 0; i < 4; ++i) xv[i] = xb[(size_t)r[i] * 64 + kt * 16 + k4];
#pragma unroll
            for (int kk = 0; kk < 4; ++kk) {
                float4 bv = wl4[(k4 * 4 + kk) * 16 + tx];   // ds_read_b128
#pragma unroll
                for (int i = 0; i < 4; ++i) {
                    const float* xf = (const float*)&xv[i];
                    float a = xf[kk];
                    acc[i][0] += a * bv.x;
                    acc[i][1] += a * bv.y;
                    acc[i][2] += a * bv.z;
                    acc[i][3] += a * bv.w;
                }
            }
        }
        __syncthreads();  // before next chunk overwrites wlds
    }

#pragma unroll
    for (int i = 0; i < 4; ++i) {
        int rr = row0 + i;
        if (rr < N_NODES) {
            float d = dis[rr];
            float4 o;
            o.x = acc[i][0] * d; o.y = acc[i][1] * d;
            o.z = acc[i][2] * d; o.w = acc[i][3] * d;
            ((float4*)s1)[(size_t)rr * 16 + tx] = o;
        }
    }
}

// ---------------- gather layer 1 + ELU ----------------
__global__ __launch_bounds__(256) void gather1(const float* __restrict__ s1,
                                               const int* __restrict__ ptr,
                                               const int* __restrict__ srcs,
                                               const float* __restrict__ dis,
                                               const float* __restrict__ b1,
                                               float* __restrict__ h1) {
    const int j = threadIdx.x & 63;
    const int v = __builtin_amdgcn_readfirstlane(blockIdx.x * 4 + (threadIdx.x >> 6));
    float acc = s1[(size_t)v * HID + j];              // self-loop term
    const int beg = ptr[v];
    const int end = (v + 1 < N_NODES) ? ptr[v + 1] : N_EDGES;
    int k = beg;
    for (; k + 8 <= end; k += 8) {
        int u0 = srcs[k],     u1 = srcs[k + 1], u2 = srcs[k + 2], u3 = srcs[k + 3];
        int u4 = srcs[k + 4], u5 = srcs[k + 5], u6 = srcs[k + 6], u7 = srcs[k + 7];
        float f0 = s1[(size_t)u0 * HID + j];
        float f1 = s1[(size_t)u1 * HID + j];
        float f2 = s1[(size_t)u2 * HID + j];
        float f3 = s1[(size_t)u3 * HID + j];
        float f4 = s1[(size_t)u4 * HID + j];
        float f5 = s1[(size_t)u5 * HID + j];
        float f6 = s1[(size_t)u6 * HID + j];
        float f7 = s1[(size_t)u7 * HID + j];
        acc += ((f0 + f1) + (f2 + f3)) + ((f4 + f5) + (f6 + f7));
    }
    for (; k < end; ++k) acc += s1[(size_t)srcs[k] * HID + j];
    float tt = dis[v] * acc + b1[j];
    h1[(size_t)v * HID + j] = tt > 0.f ? tt : (expf(tt) - 1.f);
}

// ---------------- GEMM2: s2[n][j] = dis[n] * (h1[n,:] @ W2[:,j]) ----------------
__global__ __launch_bounds__(256) void gemm2(const float* __restrict__ h,
                                             const float* __restrict__ W2,
                                             const float* __restrict__ dis,
                                             float* __restrict__ s2) {
    const int j  = threadIdx.x & 31;
    const int g  = threadIdx.x >> 5;
    const int n0 = blockIdx.x * 32 + g * 4;
    const float* h0 = h + (size_t)n0 * HID;
    float a0 = 0.f, a1 = 0.f, a2 = 0.f, a3 = 0.f;
#pragma unroll 4
    for (int k = 0; k < HID; ++k) {
        float w = W2[k * OUTC + j];
        a0 += h0[k] * w;
        a1 += h0[HID + k] * w;
        a2 += h0[2 * HID + k] * w;
        a3 += h0[3 * HID + k] * w;
    }
    size_t o = (size_t)n0 * OUTC + j;
    s2[o]            = dis[n0]     * a0;
    s2[o + OUTC]     = dis[n0 + 1] * a1;
    s2[o + 2 * OUTC] = dis[n0 + 2] * a2;
    s2[o + 3 * OUTC] = dis[n0 + 3] * a3;
}

// ---------------- gather layer 2 + ELU + final projection ----------------
__global__ __launch_bounds__(256) void gather2(const float* __restrict__ s2,
                                               const int* __restrict__ ptr,
                                               const int* __restrict__ srcs,
                                               const float* __restrict__ dis,
                                               const float* __restrict__ b2,
                                               const float* __restrict__ Wc,
                                               const float* __restrict__ bc,
                                               float* __restrict__ out) {
    const int j = threadIdx.x & 31;
    const int v = blockIdx.x * 8 + (threadIdx.x >> 5);
    float acc = s2[(size_t)v * OUTC + j];             // self-loop term
    const int beg = ptr[v];
    const int end = (v + 1 < N_NODES) ? ptr[v + 1] : N_EDGES;
    int k = beg;
    for (; k + 8 <= end; k += 8) {
        int u0 = srcs[k],     u1 = srcs[k + 1], u2 = srcs[k + 2], u3 = srcs[k + 3];
        int u4 = srcs[k + 4], u5 = srcs[k + 5], u6 = srcs[k + 6], u7 = srcs[k + 7];
        float f0 = s2[(size_t)u0 * OUTC + j];
        float f1 = s2[(size_t)u1 * OUTC + j];
        float f2 = s2[(size_t)u2 * OUTC + j];
        float f3 = s2[(size_t)u3 * OUTC + j];
        float f4 = s2[(size_t)u4 * OUTC + j];
        float f5 = s2[(size_t)u5 * OUTC + j];
        float f6 = s2[(size_t)u6 * OUTC + j];
        float f7 = s2[(size_t)u7 * OUTC + j];
        acc += ((f0 + f1) + (f2 + f3)) + ((f4 + f5) + (f6 + f7));
    }
    for (; k < end; ++k) acc += s2[(size_t)srcs[k] * OUTC + j];
    float t = dis[v] * acc + b2[j];
    float hh = t > 0.f ? t : (expf(t) - 1.f);
    float p = hh * Wc[j];
#pragma unroll
    for (int off = 16; off > 0; off >>= 1) p += __shfl_xor(p, off, 64);
    if (j == 0) out[v] = p + bc[0];
}

extern "C" void kernel_launch(void* const* d_in, const int* in_sizes, int n_in,
                              void* d_out, int out_size, void* d_ws, size_t ws_size,
                              hipStream_t stream) {
    const float* x  = (const float*)d_in[0];
    const int*   ei = (const int*)d_in[1];
    const float* W1 = (const float*)d_in[2];
    const float* b1 = (const float*)d_in[3];
    const float* W2 = (const float*)d_in[4];
    const float* b2 = (const float*)d_in[5];
    const float* Wc = (const float*)d_in[6];
    const float* bc = (const float*)d_in[7];
    float* out = (float*)d_out;

    const int* row = ei;            // edge_index[0] = source
    const int* col = ei + N_EDGES;  // edge_index[1] = target

    char* ws = (char*)d_ws;
    int*   deg  = (int*)  (ws + OFF_DEG);
    int*   ptr  = (int*)  (ws + OFF_PTR);
    int*   bsum = (int*)  (ws + OFF_BSUM);
    int*   gcur = (int*)  (ws + OFF_GCUR);
    float* dis  = (float*)(ws + OFF_DIS);
    int*   srcs = (int*)  (ws + OFF_SRC);
    float* s1   = (float*)(ws + OFF_S1);
    float* h1   = (float*)(ws + OFF_H1);
    float* s2   = (float*)(ws + OFF_S1);   // reuse (dead after gather1)
    int*   part = (int*)  (ws + OFF_S1);   // partition buffer aliases s1/h1 (dead before gemm1)

    bucket_init    <<<(NBUCK + 255) / 256, 256, 0, stream>>>(gcur);
    partition_edges<<<(N_EDGES + CHUNK - 1) / CHUNK, 256, 0, stream>>>(row, col, gcur, part);
    bucket_hist    <<<NBUCK, 256, 0, stream>>>(gcur, part, deg);
    compute_dis    <<<NB, 256, 0, stream>>>(deg, dis);
    scan_block_sums<<<NB, 256, 0, stream>>>(deg, bsum);
    scan_bsum      <<<1, 512, 0, stream>>>(bsum);
    scan_block_scan<<<NB, 256, 0, stream>>>(deg, bsum, ptr);
    bucket_fill    <<<NBUCK, 256, 0, stream>>>(gcur, part, ptr, srcs);

    gemm1  <<<(N_NODES + 63) / 64, 256, 0, stream>>>(x, W1, dis, s1);
    gather1<<<N_NODES / 4, 256, 0, stream>>>(s1, ptr, srcs, dis, b1, h1);
    gemm2  <<<N_NODES / 32, 256, 0, stream>>>(h1, W2, dis, s2);
    gather2<<<N_NODES / 8, 256, 0, stream>>>(s2, ptr, srcs, dis, b2, Wc, bc, out);
}

// Round 9
// 489.562 us; speedup vs baseline: 1.4680x; 1.0932x over previous
//
#include <hip/hip_runtime.h>
#include <hip/hip_fp16.h>
#include <math.h>

#define N_NODES 100000
#define N_EDGES 3200000
#define IN_CH   256
#define HID     64
#define OUTC    32
#define NB      ((N_NODES + 255) / 256)   // 391 (scan blocks, also node buckets)
#define NBUCK   ((N_NODES + 255) / 256)   // 391 buckets of 256 nodes (bucket = dst >> 8)
#define CHUNK   8192                      // edges per partition block
#define CAP     9216                      // bucket capacity: mean 8192, sigma ~90 -> +11 sigma

// ---------------- workspace layout (bytes) ----------------
static constexpr size_t align256(size_t x) { return (x + 255) & ~(size_t)255; }
static constexpr size_t OFF_DEG  = 0;                                          // N ints
static constexpr size_t OFF_PTR  = OFF_DEG  + align256((size_t)N_NODES * 4);   // N ints (exclusive)
static constexpr size_t OFF_BSUM = OFF_PTR  + align256((size_t)N_NODES * 4);   // 512 ints
static constexpr size_t OFF_GCUR = OFF_BSUM + align256(512 * 4);               // NBUCK ints
static constexpr size_t OFF_DIS  = OFF_GCUR + align256((size_t)NBUCK * 4);     // N floats
static constexpr size_t OFF_SRC  = OFF_DIS  + align256((size_t)N_NODES * 4);   // E ints
static constexpr size_t OFF_PART = OFF_SRC  + align256((size_t)N_EDGES * 4);   // NBUCK*CAP ints (14.4 MB)
// s1h (N*64 halves = 12.8 MB) aliases PART (part dead after bucket_fill, before gemm1)
static constexpr size_t OFF_S1   = OFF_PART;
static constexpr size_t OFF_H1   = OFF_PART + align256((size_t)NBUCK * CAP * 4);  // N*64 floats (25.6 MB)
static constexpr size_t OFF_S2   = OFF_H1 + align256((size_t)N_NODES * HID * 4);  // N*32 halves (6.4 MB)
// total ~60 MB

// ---------------- bucket cursor init: gcur[b] = b*CAP ----------------
__global__ __launch_bounds__(256) void bucket_init(int* __restrict__ gcur) {
    int b = blockIdx.x * 256 + threadIdx.x;
    if (b < NBUCK) gcur[b] = b * CAP;
}

// ---------------- phase A: partition edges into coarse dst-buckets ----------------
// packed entry: src (17 bits) | dst_low8 << 17
__global__ __launch_bounds__(256) void partition_edges(const int* __restrict__ row,
                                                       const int* __restrict__ col,
                                                       int* __restrict__ gcur,
                                                       int* __restrict__ part) {
    __shared__ int lhist[NBUCK];
    __shared__ int lbase[NBUCK];
    __shared__ int lrank[NBUCK];
    const int t  = threadIdx.x;
    const int e0 = blockIdx.x * CHUNK;
    const int e1 = min(e0 + CHUNK, N_EDGES);
    for (int i = t; i < NBUCK; i += 256) { lhist[i] = 0; lrank[i] = 0; }
    __syncthreads();
    for (int e = e0 + t; e < e1; e += 256) {
        atomicAdd(&lhist[col[e] >> 8], 1);
    }
    __syncthreads();
    for (int i = t; i < NBUCK; i += 256) {
        int c = lhist[i];
        lbase[i] = (c > 0) ? atomicAdd(&gcur[i], c) : 0;
    }
    __syncthreads();
    for (int e = e0 + t; e < e1; e += 256) {
        int d = col[e];
        int b = d >> 8;
        int r = atomicAdd(&lrank[b], 1);
        part[lbase[b] + r] = row[e] | ((d & 255) << 17);
    }
}

// ---------------- phase B1: per-node degree from bucket data (dense writes) ----------
__global__ __launch_bounds__(256) void bucket_hist(const int* __restrict__ gcur,
                                                   const int* __restrict__ part,
                                                   int* __restrict__ deg) {
    __shared__ int lh[256];
    const int b = blockIdx.x;
    lh[threadIdx.x] = 0;
    __syncthreads();
    const int cnt = gcur[b] - b * CAP;
    for (int i = threadIdx.x; i < cnt; i += 256)
        atomicAdd(&lh[part[(size_t)b * CAP + i] >> 17], 1);
    __syncthreads();
    int v = b * 256 + threadIdx.x;
    if (v < N_NODES) deg[v] = lh[threadIdx.x];
}

__global__ __launch_bounds__(256) void compute_dis(const int* __restrict__ deg,
                                                   float* __restrict__ dis) {
    unsigned v = blockIdx.x * 256u + threadIdx.x;
    if (v < N_NODES) dis[v] = rsqrtf((float)deg[v] + 1.0f);  // +1 self-loop
}

// ---------------- 3-kernel exclusive scan of deg -> ptr ----------------
__global__ __launch_bounds__(256) void scan_block_sums(const int* __restrict__ deg,
                                                       int* __restrict__ bsum) {
    __shared__ int buf[256];
    unsigned i = blockIdx.x * 256u + threadIdx.x;
    int v = (i < N_NODES) ? deg[i] : 0;
    buf[threadIdx.x] = v;
    __syncthreads();
    for (int off = 128; off > 0; off >>= 1) {
        if (threadIdx.x < (unsigned)off) buf[threadIdx.x] += buf[threadIdx.x + off];
        __syncthreads();
    }
    if (threadIdx.x == 0) bsum[blockIdx.x] = buf[0];
}

__global__ __launch_bounds__(512) void scan_bsum(int* __restrict__ bsum) {
    __shared__ int buf[512];
    int t = threadIdx.x;
    int v = (t < NB) ? bsum[t] : 0;
    buf[t] = v;
    __syncthreads();
    for (int off = 1; off < 512; off <<= 1) {
        int add = (t >= off) ? buf[t - off] : 0;
        __syncthreads();
        buf[t] += add;
        __syncthreads();
    }
    if (t < NB) bsum[t] = buf[t] - v;  // exclusive
}

__global__ __launch_bounds__(256) void scan_block_scan(const int* __restrict__ deg,
                                                       const int* __restrict__ bsum,
                                                       int* __restrict__ ptr) {
    __shared__ int buf[256];
    unsigned i = blockIdx.x * 256u + threadIdx.x;
    int v = (i < N_NODES) ? deg[i] : 0;
    buf[threadIdx.x] = v;
    __syncthreads();
    for (int off = 1; off < 256; off <<= 1) {
        int add = (threadIdx.x >= (unsigned)off) ? buf[threadIdx.x - off] : 0;
        __syncthreads();
        buf[threadIdx.x] += add;
        __syncthreads();
    }
    if (i < N_NODES) ptr[i] = bsum[blockIdx.x] + buf[threadIdx.x] - v;  // exclusive
}

// ---------------- phase B2: fill srcs; writes confined to ~32KB window/block -------
__global__ __launch_bounds__(256) void bucket_fill(const int* __restrict__ gcur,
                                                   const int* __restrict__ part,
                                                   const int* __restrict__ ptr,
                                                   int* __restrict__ srcs) {
    __shared__ int lcur[256];
    const int b = blockIdx.x;
    lcur[threadIdx.x] = 0;
    __syncthreads();
    const int cnt = gcur[b] - b * CAP;
    for (int i = threadIdx.x; i < cnt; i += 256) {
        int p    = part[(size_t)b * CAP + i];
        int dlow = p >> 17;
        int src  = p & 0x1FFFF;
        int r    = atomicAdd(&lcur[dlow], 1);        // LDS cursor
        srcs[ptr[b * 256 + dlow] + r] = src;
    }
}

// ---------------- GEMM1: s1h[n][j] = fp16(dis[n] * (x[n,:] @ W1[:,j])) ----------
// Register-blocked tile GEMM; operand streams on different wait counters:
// W1 k-chunks -> LDS (lgkmcnt), x -> per-lane VMEM (vmcnt). 256 thr = 16x16,
// 4x4 fragment; M-tile 64, K chunk 64. Epilogue packs fp16 (halves gather BW).
__global__ __launch_bounds__(256) void gemm1(const float* __restrict__ x,
                                             const float* __restrict__ W1,
                                             const float* __restrict__ dis,
                                             __half* __restrict__ s1h) {
    __shared__ float wlds[64 * HID];  // 16 KB k-chunk: [k_local][j]

    const int t  = threadIdx.x;
    const int tx = t & 15;   // col group: cols tx*4 .. tx*4+3
    const int ty = t >> 4;   // row group: rows ty*4 .. ty*4+3
    const int row0 = blockIdx.x * 64 + ty * 4;

    int r[4];
#pragma unroll
    for (int i = 0; i < 4; ++i) {
        int rr = row0 + i;
        r[i] = rr < N_NODES ? rr : N_NODES - 1;   // clamp (garbage compute, guarded store)
    }

    const float4* xb = (const float4*)x;          // row rr: 64 float4s
    float acc[4][4] = {{0.f}};

    for (int kt = 0; kt < IN_CH / 64; ++kt) {
        {
            const float4* w4 = (const float4*)(W1 + (size_t)kt * 64 * HID);
            float4* l4 = (float4*)wlds;
#pragma unroll
            for (int i = 0; i < 4; ++i) l4[i * 256 + t] = w4[i * 256 + t];
        }
        __syncthreads();

        const float4* wl4 = (const float4*)wlds;
#pragma unroll 4
        for (int k4 = 0; k4 < 16; ++k4) {
            float4 xv[4];
#pragma unroll
            for (int i = 0; i < 4; ++i) xv[i] = xb[(size_t)r[i] * 64 + kt * 16 + k4];
#pragma unroll
            for (int kk = 0; kk < 4; ++kk) {
                float4 bv = wl4[(k4 * 4 + kk) * 16 + tx];   // ds_read_b128
#pragma unroll
                for (int i = 0; i < 4; ++i) {
                    const float* xf = (const float*)&xv[i];
                    float a = xf[kk];
                    acc[i][0] += a * bv.x;
                    acc[i][1] += a * bv.y;
                    acc[i][2] += a * bv.z;
                    acc[i][3] += a * bv.w;
                }
            }
        }
        __syncthreads();
    }

#pragma unroll
    for (int i = 0; i < 4; ++i) {
        int rr = row0 + i;
        if (rr < N_NODES) {
            float d = dis[rr];
            __half2 p0 = __floats2half2_rn(acc[i][0] * d, acc[i][1] * d);
            __half2 p1 = __floats2half2_rn(acc[i][2] * d, acc[i][3] * d);
            __half2* dst = (__half2*)(s1h + (size_t)rr * HID + tx * 4);
            dst[0] = p0;
            dst[1] = p1;
        }
    }
}

// ---------------- gather layer 1 + ELU: h1 fp32 from fp16 s1 ----------------
// one wave per node (64 lanes = 64 features, 128 B = 2 lines per edge row).
__global__ __launch_bounds__(256) void gather1(const __half* __restrict__ s1h,
                                               const int* __restrict__ ptr,
                                               const int* __restrict__ srcs,
                                               const float* __restrict__ dis,
                                               const float* __restrict__ b1,
                                               float* __restrict__ h1) {
    const int j = threadIdx.x & 63;
    const int v = __builtin_amdgcn_readfirstlane(blockIdx.x * 4 + (threadIdx.x >> 6));
    float acc = __half2float(s1h[(size_t)v * HID + j]);   // self-loop term
    const int beg = ptr[v];
    const int end = (v + 1 < N_NODES) ? ptr[v + 1] : N_EDGES;
    int k = beg;
    for (; k + 8 <= end; k += 8) {
        int u0 = srcs[k],     u1 = srcs[k + 1], u2 = srcs[k + 2], u3 = srcs[k + 3];
        int u4 = srcs[k + 4], u5 = srcs[k + 5], u6 = srcs[k + 6], u7 = srcs[k + 7];
        float f0 = __half2float(s1h[(size_t)u0 * HID + j]);
        float f1 = __half2float(s1h[(size_t)u1 * HID + j]);
        float f2 = __half2float(s1h[(size_t)u2 * HID + j]);
        float f3 = __half2float(s1h[(size_t)u3 * HID + j]);
        float f4 = __half2float(s1h[(size_t)u4 * HID + j]);
        float f5 = __half2float(s1h[(size_t)u5 * HID + j]);
        float f6 = __half2float(s1h[(size_t)u6 * HID + j]);
        float f7 = __half2float(s1h[(size_t)u7 * HID + j]);
        acc += ((f0 + f1) + (f2 + f3)) + ((f4 + f5) + (f6 + f7));
    }
    for (; k < end; ++k) acc += __half2float(s1h[(size_t)srcs[k] * HID + j]);
    float tt = dis[v] * acc + b1[j];
    h1[(size_t)v * HID + j] = tt > 0.f ? tt : (expf(tt) - 1.f);
}

// ---------------- GEMM2: s2h[n][j] = fp16(dis[n] * (h1[n,:] @ W2[:,j])) --------
__global__ __launch_bounds__(256) void gemm2(const float* __restrict__ h,
                                             const float* __restrict__ W2,
                                             const float* __restrict__ dis,
                                             __half* __restrict__ s2h) {
    const int j  = threadIdx.x & 31;
    const int g  = threadIdx.x >> 5;
    const int n0 = blockIdx.x * 32 + g * 4;
    const float* h0 = h + (size_t)n0 * HID;
    float a0 = 0.f, a1 = 0.f, a2 = 0.f, a3 = 0.f;
#pragma unroll 4
    for (int k = 0; k < HID; ++k) {
        float w = W2[k * OUTC + j];
        a0 += h0[k] * w;
        a1 += h0[HID + k] * w;
        a2 += h0[2 * HID + k] * w;
        a3 += h0[3 * HID + k] * w;
    }
    size_t o = (size_t)n0 * OUTC + j;
    s2h[o]            = __float2half(dis[n0]     * a0);
    s2h[o + OUTC]     = __float2half(dis[n0 + 1] * a1);
    s2h[o + 2 * OUTC] = __float2half(dis[n0 + 2] * a2);
    s2h[o + 3 * OUTC] = __float2half(dis[n0 + 3] * a3);
}

// ---------------- gather layer 2 + ELU + final projection ----------------
// 32 lanes per node; each edge row = 32 halves = 64 B = exactly one line.
__global__ __launch_bounds__(256) void gather2(const __half* __restrict__ s2h,
                                               const int* __restrict__ ptr,
                                               const int* __restrict__ srcs,
                                               const float* __restrict__ dis,
                                               const float* __restrict__ b2,
                                               const float* __restrict__ Wc,
                                               const float* __restrict__ bc,
                                               float* __restrict__ out) {
    const int j = threadIdx.x & 31;
    const int v = blockIdx.x * 8 + (threadIdx.x >> 5);
    float acc = __half2float(s2h[(size_t)v * OUTC + j]);  // self-loop term
    const int beg = ptr[v];
    const int end = (v + 1 < N_NODES) ? ptr[v + 1] : N_EDGES;
    int k = beg;
    for (; k + 8 <= end; k += 8) {
        int u0 = srcs[k],     u1 = srcs[k + 1], u2 = srcs[k + 2], u3 = srcs[k + 3];
        int u4 = srcs[k + 4], u5 = srcs[k + 5], u6 = srcs[k + 6], u7 = srcs[k + 7];
        float f0 = __half2float(s2h[(size_t)u0 * OUTC + j]);
        float f1 = __half2float(s2h[(size_t)u1 * OUTC + j]);
        float f2 = __half2float(s2h[(size_t)u2 * OUTC + j]);
        float f3 = __half2float(s2h[(size_t)u3 * OUTC + j]);
        float f4 = __half2float(s2h[(size_t)u4 * OUTC + j]);
        float f5 = __half2float(s2h[(size_t)u5 * OUTC + j]);
        float f6 = __half2float(s2h[(size_t)u6 * OUTC + j]);
        float f7 = __half2float(s2h[(size_t)u7 * OUTC + j]);
        acc += ((f0 + f1) + (f2 + f3)) + ((f4 + f5) + (f6 + f7));
    }
    for (; k < end; ++k) acc += __half2float(s2h[(size_t)srcs[k] * OUTC + j]);
    float t = dis[v] * acc + b2[j];
    float hh = t > 0.f ? t : (expf(t) - 1.f);
    float p = hh * Wc[j];
#pragma unroll
    for (int off = 16; off > 0; off >>= 1) p += __shfl_xor(p, off, 64);
    if (j == 0) out[v] = p + bc[0];
}

extern "C" void kernel_launch(void* const* d_in, const int* in_sizes, int n_in,
                              void* d_out, int out_size, void* d_ws, size_t ws_size,
                              hipStream_t stream) {
    const float* x  = (const float*)d_in[0];
    const int*   ei = (const int*)d_in[1];
    const float* W1 = (const float*)d_in[2];
    const float* b1 = (const float*)d_in[3];
    const float* W2 = (const float*)d_in[4];
    const float* b2 = (const float*)d_in[5];
    const float* Wc = (const float*)d_in[6];
    const float* bc = (const float*)d_in[7];
    float* out = (float*)d_out;

    const int* row = ei;            // edge_index[0] = source
    const int* col = ei + N_EDGES;  // edge_index[1] = target

    char* ws = (char*)d_ws;
    int*    deg  = (int*)   (ws + OFF_DEG);
    int*    ptr  = (int*)   (ws + OFF_PTR);
    int*    bsum = (int*)   (ws + OFF_BSUM);
    int*    gcur = (int*)   (ws + OFF_GCUR);
    float*  dis  = (float*) (ws + OFF_DIS);
    int*    srcs = (int*)   (ws + OFF_SRC);
    int*    part = (int*)   (ws + OFF_PART);
    __half* s1h  = (__half*)(ws + OFF_S1);    // aliases part (part dead before gemm1)
    float*  h1   = (float*) (ws + OFF_H1);
    __half* s2h  = (__half*)(ws + OFF_S2);

    bucket_init    <<<(NBUCK + 255) / 256, 256, 0, stream>>>(gcur);
    partition_edges<<<(N_EDGES + CHUNK - 1) / CHUNK, 256, 0, stream>>>(row, col, gcur, part);
    bucket_hist    <<<NBUCK, 256, 0, stream>>>(gcur, part, deg);
    compute_dis    <<<NB, 256, 0, stream>>>(deg, dis);
    scan_block_sums<<<NB, 256, 0, stream>>>(deg, bsum);
    scan_bsum      <<<1, 512, 0, stream>>>(bsum);
    scan_block_scan<<<NB, 256, 0, stream>>>(deg, bsum, ptr);
    bucket_fill    <<<NBUCK, 256, 0, stream>>>(gcur, part, ptr, srcs);

    gemm1  <<<(N_NODES + 63) / 64, 256, 0, stream>>>(x, W1, dis, s1h);
    gather1<<<N_NODES / 4, 256, 0, stream>>>(s1h, ptr, srcs, dis, b1, h1);
    gemm2  <<<N_NODES / 32, 256, 0, stream>>>(h1, W2, dis, s2h);
    gather2<<<N_NODES / 8, 256, 0, stream>>>(s2h, ptr, srcs, dis, b2, Wc, bc, out);
}

// Round 10
// 471.299 us; speedup vs baseline: 1.5249x; 1.0388x over previous
//
#include <hip/hip_runtime.h>
#include <hip/hip_fp16.h>
#include <math.h>

#define N_NODES 100000
#define N_EDGES 3200000
#define IN_CH   256
#define HID     64
#define OUTC    32
#define NB      ((N_NODES + 255) / 256)   // 391 (scan blocks, also node buckets)
#define NBUCK   ((N_NODES + 255) / 256)   // 391 buckets of 256 nodes (bucket = dst >> 8)
#define CHUNK   8192                      // edges per partition block
#define CAP     9216                      // bucket capacity: mean 8192, sigma ~90 -> +11 sigma

// ---------------- workspace layout (bytes) ----------------
static constexpr size_t align256(size_t x) { return (x + 255) & ~(size_t)255; }
static constexpr size_t OFF_DEG  = 0;                                          // N ints
static constexpr size_t OFF_PTR  = OFF_DEG  + align256((size_t)N_NODES * 4);   // N ints (exclusive)
static constexpr size_t OFF_BSUM = OFF_PTR  + align256((size_t)N_NODES * 4);   // 512 ints
static constexpr size_t OFF_GCUR = OFF_BSUM + align256(512 * 4);               // NBUCK ints
static constexpr size_t OFF_DIS  = OFF_GCUR + align256((size_t)NBUCK * 4);     // N floats
static constexpr size_t OFF_SRC  = OFF_DIS  + align256((size_t)N_NODES * 4);   // E ints
static constexpr size_t OFF_PART = OFF_SRC  + align256((size_t)N_EDGES * 4);   // NBUCK*CAP ints (14.4 MB)
// s1h (N*64 halves = 12.8 MB) aliases PART (part dead after bucket_fill, before gemm1)
static constexpr size_t OFF_S1   = OFF_PART;
static constexpr size_t OFF_H1   = OFF_PART + align256((size_t)NBUCK * CAP * 4);  // N*64 floats (25.6 MB)
static constexpr size_t OFF_S2   = OFF_H1 + align256((size_t)N_NODES * HID * 4);  // N*32 halves (6.4 MB)
// total ~60 MB

// ---------------- bucket cursor init: gcur[b] = b*CAP ----------------
__global__ __launch_bounds__(256) void bucket_init(int* __restrict__ gcur) {
    int b = blockIdx.x * 256 + threadIdx.x;
    if (b < NBUCK) gcur[b] = b * CAP;
}

// ---------------- phase A: partition edges into coarse dst-buckets ----------------
// packed entry: src (17 bits) | dst_low8 << 17
__global__ __launch_bounds__(256) void partition_edges(const int* __restrict__ row,
                                                       const int* __restrict__ col,
                                                       int* __restrict__ gcur,
                                                       int* __restrict__ part) {
    __shared__ int lhist[NBUCK];
    __shared__ int lbase[NBUCK];
    __shared__ int lrank[NBUCK];
    const int t  = threadIdx.x;
    const int e0 = blockIdx.x * CHUNK;
    const int e1 = min(e0 + CHUNK, N_EDGES);
    for (int i = t; i < NBUCK; i += 256) { lhist[i] = 0; lrank[i] = 0; }
    __syncthreads();
    for (int e = e0 + t; e < e1; e += 256) {
        atomicAdd(&lhist[col[e] >> 8], 1);
    }
    __syncthreads();
    for (int i = t; i < NBUCK; i += 256) {
        int c = lhist[i];
        lbase[i] = (c > 0) ? atomicAdd(&gcur[i], c) : 0;
    }
    __syncthreads();
    for (int e = e0 + t; e < e1; e += 256) {
        int d = col[e];
        int b = d >> 8;
        int r = atomicAdd(&lrank[b], 1);
        part[lbase[b] + r] = row[e] | ((d & 255) << 17);
    }
}

// ---------------- phase B1: per-node degree from bucket data (dense writes) ----------
__global__ __launch_bounds__(256) void bucket_hist(const int* __restrict__ gcur,
                                                   const int* __restrict__ part,
                                                   int* __restrict__ deg) {
    __shared__ int lh[256];
    const int b = blockIdx.x;
    lh[threadIdx.x] = 0;
    __syncthreads();
    const int cnt = gcur[b] - b * CAP;
    for (int i = threadIdx.x; i < cnt; i += 256)
        atomicAdd(&lh[part[(size_t)b * CAP + i] >> 17], 1);
    __syncthreads();
    int v = b * 256 + threadIdx.x;
    if (v < N_NODES) deg[v] = lh[threadIdx.x];
}

__global__ __launch_bounds__(256) void compute_dis(const int* __restrict__ deg,
                                                   float* __restrict__ dis) {
    unsigned v = blockIdx.x * 256u + threadIdx.x;
    if (v < N_NODES) dis[v] = rsqrtf((float)deg[v] + 1.0f);  // +1 self-loop
}

// ---------------- 3-kernel exclusive scan of deg -> ptr ----------------
__global__ __launch_bounds__(256) void scan_block_sums(const int* __restrict__ deg,
                                                       int* __restrict__ bsum) {
    __shared__ int buf[256];
    unsigned i = blockIdx.x * 256u + threadIdx.x;
    int v = (i < N_NODES) ? deg[i] : 0;
    buf[threadIdx.x] = v;
    __syncthreads();
    for (int off = 128; off > 0; off >>= 1) {
        if (threadIdx.x < (unsigned)off) buf[threadIdx.x] += buf[threadIdx.x + off];
        __syncthreads();
    }
    if (threadIdx.x == 0) bsum[blockIdx.x] = buf[0];
}

__global__ __launch_bounds__(512) void scan_bsum(int* __restrict__ bsum) {
    __shared__ int buf[512];
    int t = threadIdx.x;
    int v = (t < NB) ? bsum[t] : 0;
    buf[t] = v;
    __syncthreads();
    for (int off = 1; off < 512; off <<= 1) {
        int add = (t >= off) ? buf[t - off] : 0;
        __syncthreads();
        buf[t] += add;
        __syncthreads();
    }
    if (t < NB) bsum[t] = buf[t] - v;  // exclusive
}

__global__ __launch_bounds__(256) void scan_block_scan(const int* __restrict__ deg,
                                                       const int* __restrict__ bsum,
                                                       int* __restrict__ ptr) {
    __shared__ int buf[256];
    unsigned i = blockIdx.x * 256u + threadIdx.x;
    int v = (i < N_NODES) ? deg[i] : 0;
    buf[threadIdx.x] = v;
    __syncthreads();
    for (int off = 1; off < 256; off <<= 1) {
        int add = (threadIdx.x >= (unsigned)off) ? buf[threadIdx.x - off] : 0;
        __syncthreads();
        buf[threadIdx.x] += add;
        __syncthreads();
    }
    if (i < N_NODES) ptr[i] = bsum[blockIdx.x] + buf[threadIdx.x] - v;  // exclusive
}

// ---------------- phase B2: fill srcs; writes confined to ~32KB window/block -------
__global__ __launch_bounds__(256) void bucket_fill(const int* __restrict__ gcur,
                                                   const int* __restrict__ part,
                                                   const int* __restrict__ ptr,
                                                   int* __restrict__ srcs) {
    __shared__ int lcur[256];
    const int b = blockIdx.x;
    lcur[threadIdx.x] = 0;
    __syncthreads();
    const int cnt = gcur[b] - b * CAP;
    for (int i = threadIdx.x; i < cnt; i += 256) {
        int p    = part[(size_t)b * CAP + i];
        int dlow = p >> 17;
        int src  = p & 0x1FFFF;
        int r    = atomicAdd(&lcur[dlow], 1);        // LDS cursor
        srcs[ptr[b * 256 + dlow] + r] = src;
    }
}

// ---------------- GEMM1: s1h[n][j] = fp16(dis[n] * (x[n,:] @ W1[:,j])) ----------
// Both operands staged in LDS. x-tile staged with fully-coalesced VMEM (each
// thread loads 4 DISTINCT float4s -> 20 VMEM inst/thread total, vs 256
// 16-way-duplicated broadcast loads in r9 -> TA address pressure gone).
// Inner loop: 8 ds_read_b128 (x: 4-addr w/ 2-way bank alias via 68-float row
// pad = free; W1: contiguous) + 64 v_fmac per k4-step -> VALU-bound.
// 256 thr = 16x16, 4x4 frag; M-tile 64, K chunk 64; LDS 33 KB -> ~4 blk/CU.
__global__ __launch_bounds__(256) void gemm1(const float* __restrict__ x,
                                             const float* __restrict__ W1,
                                             const float* __restrict__ dis,
                                             __half* __restrict__ s1h) {
    __shared__ float wlds[64 * HID];   // 16 KB k-chunk of W1: [k_local][j]
    __shared__ float xlds[64 * 68];    // 17 KB x-tile: [row_local][k_local], stride 68

    const int t  = threadIdx.x;
    const int tx = t & 15;   // col group: cols tx*4 .. tx*4+3
    const int ty = t >> 4;   // row group: rows ty*4 .. ty*4+3
    const int row0 = blockIdx.x * 64;

    float acc[4][4] = {{0.f}};

    for (int kt = 0; kt < IN_CH / 64; ++kt) {
        // stage W1 rows [kt*64, kt*64+64) -> LDS, coalesced float4
        {
            const float4* w4 = (const float4*)(W1 + (size_t)kt * 64 * HID);
            float4* l4 = (float4*)wlds;
#pragma unroll
            for (int i = 0; i < 4; ++i) l4[i * 256 + t] = w4[i * 256 + t];
        }
        // stage x tile (64 rows x 64 k) -> LDS, coalesced float4 (1024 distinct)
        {
#pragma unroll
            for (int i = 0; i < 4; ++i) {
                int L  = i * 256 + t;       // 0..1023
                int rl = L >> 4;            // row local 0..63
                int k4 = L & 15;            // float4 index within the k-chunk
                int rg = row0 + rl;
                float4 v;
                if (rg < N_NODES) v = ((const float4*)x)[(size_t)rg * 64 + kt * 16 + k4];
                else              v = make_float4(0.f, 0.f, 0.f, 0.f);
                *(float4*)(&xlds[rl * 68 + k4 * 4]) = v;
            }
        }
        __syncthreads();

        const float4* wl4 = (const float4*)wlds;
#pragma unroll 4
        for (int k4 = 0; k4 < 16; ++k4) {
            float4 xv[4];
#pragma unroll
            for (int i = 0; i < 4; ++i)
                xv[i] = *(const float4*)(&xlds[(ty * 4 + i) * 68 + k4 * 4]);
#pragma unroll
            for (int kk = 0; kk < 4; ++kk) {
                float4 bv = wl4[(k4 * 4 + kk) * 16 + tx];   // ds_read_b128
#pragma unroll
                for (int i = 0; i < 4; ++i) {
                    const float* xf = (const float*)&xv[i];
                    float a = xf[kk];
                    acc[i][0] += a * bv.x;
                    acc[i][1] += a * bv.y;
                    acc[i][2] += a * bv.z;
                    acc[i][3] += a * bv.w;
                }
            }
        }
        __syncthreads();  // before next chunk overwrites LDS
    }

#pragma unroll
    for (int i = 0; i < 4; ++i) {
        int rr = row0 + ty * 4 + i;
        if (rr < N_NODES) {
            float d = dis[rr];
            __half2 p0 = __floats2half2_rn(acc[i][0] * d, acc[i][1] * d);
            __half2 p1 = __floats2half2_rn(acc[i][2] * d, acc[i][3] * d);
            __half2* dst = (__half2*)(s1h + (size_t)rr * HID + tx * 4);
            dst[0] = p0;
            dst[1] = p1;
        }
    }
}

// ---------------- gather layer 1 + ELU: h1 fp32 from fp16 s1 ----------------
__global__ __launch_bounds__(256) void gather1(const __half* __restrict__ s1h,
                                               const int* __restrict__ ptr,
                                               const int* __restrict__ srcs,
                                               const float* __restrict__ dis,
                                               const float* __restrict__ b1,
                                               float* __restrict__ h1) {
    const int j = threadIdx.x & 63;
    const int v = __builtin_amdgcn_readfirstlane(blockIdx.x * 4 + (threadIdx.x >> 6));
    float acc = __half2float(s1h[(size_t)v * HID + j]);   // self-loop term
    const int beg = ptr[v];
    const int end = (v + 1 < N_NODES) ? ptr[v + 1] : N_EDGES;
    int k = beg;
    for (; k + 8 <= end; k += 8) {
        int u0 = srcs[k],     u1 = srcs[k + 1], u2 = srcs[k + 2], u3 = srcs[k + 3];
        int u4 = srcs[k + 4], u5 = srcs[k + 5], u6 = srcs[k + 6], u7 = srcs[k + 7];
        float f0 = __half2float(s1h[(size_t)u0 * HID + j]);
        float f1 = __half2float(s1h[(size_t)u1 * HID + j]);
        float f2 = __half2float(s1h[(size_t)u2 * HID + j]);
        float f3 = __half2float(s1h[(size_t)u3 * HID + j]);
        float f4 = __half2float(s1h[(size_t)u4 * HID + j]);
        float f5 = __half2float(s1h[(size_t)u5 * HID + j]);
        float f6 = __half2float(s1h[(size_t)u6 * HID + j]);
        float f7 = __half2float(s1h[(size_t)u7 * HID + j]);
        acc += ((f0 + f1) + (f2 + f3)) + ((f4 + f5) + (f6 + f7));
    }
    for (; k < end; ++k) acc += __half2float(s1h[(size_t)srcs[k] * HID + j]);
    float tt = dis[v] * acc + b1[j];
    h1[(size_t)v * HID + j] = tt > 0.f ? tt : (expf(tt) - 1.f);
}

// ---------------- GEMM2: s2h[n][j] = fp16(dis[n] * (h1[n,:] @ W2[:,j])) --------
__global__ __launch_bounds__(256) void gemm2(const float* __restrict__ h,
                                             const float* __restrict__ W2,
                                             const float* __restrict__ dis,
                                             __half* __restrict__ s2h) {
    const int j  = threadIdx.x & 31;
    const int g  = threadIdx.x >> 5;
    const int n0 = blockIdx.x * 32 + g * 4;
    const float* h0 = h + (size_t)n0 * HID;
    float a0 = 0.f, a1 = 0.f, a2 = 0.f, a3 = 0.f;
#pragma unroll 4
    for (int k = 0; k < HID; ++k) {
        float w = W2[k * OUTC + j];
        a0 += h0[k] * w;
        a1 += h0[HID + k] * w;
        a2 += h0[2 * HID + k] * w;
        a3 += h0[3 * HID + k] * w;
    }
    size_t o = (size_t)n0 * OUTC + j;
    s2h[o]            = __float2half(dis[n0]     * a0);
    s2h[o + OUTC]     = __float2half(dis[n0 + 1] * a1);
    s2h[o + 2 * OUTC] = __float2half(dis[n0 + 2] * a2);
    s2h[o + 3 * OUTC] = __float2half(dis[n0 + 3] * a3);
}

// ---------------- gather layer 2 + ELU + final projection ----------------
__global__ __launch_bounds__(256) void gather2(const __half* __restrict__ s2h,
                                               const int* __restrict__ ptr,
                                               const int* __restrict__ srcs,
                                               const float* __restrict__ dis,
                                               const float* __restrict__ b2,
                                               const float* __restrict__ Wc,
                                               const float* __restrict__ bc,
                                               float* __restrict__ out) {
    const int j = threadIdx.x & 31;
    const int v = blockIdx.x * 8 + (threadIdx.x >> 5);
    float acc = __half2float(s2h[(size_t)v * OUTC + j]);  // self-loop term
    const int beg = ptr[v];
    const int end = (v + 1 < N_NODES) ? ptr[v + 1] : N_EDGES;
    int k = beg;
    for (; k + 8 <= end; k += 8) {
        int u0 = srcs[k],     u1 = srcs[k + 1], u2 = srcs[k + 2], u3 = srcs[k + 3];
        int u4 = srcs[k + 4], u5 = srcs[k + 5], u6 = srcs[k + 6], u7 = srcs[k + 7];
        float f0 = __half2float(s2h[(size_t)u0 * OUTC + j]);
        float f1 = __half2float(s2h[(size_t)u1 * OUTC + j]);
        float f2 = __half2float(s2h[(size_t)u2 * OUTC + j]);
        float f3 = __half2float(s2h[(size_t)u3 * OUTC + j]);
        float f4 = __half2float(s2h[(size_t)u4 * OUTC + j]);
        float f5 = __half2float(s2h[(size_t)u5 * OUTC + j]);
        float f6 = __half2float(s2h[(size_t)u6 * OUTC + j]);
        float f7 = __half2float(s2h[(size_t)u7 * OUTC + j]);
        acc += ((f0 + f1) + (f2 + f3)) + ((f4 + f5) + (f6 + f7));
    }
    for (; k < end; ++k) acc += __half2float(s2h[(size_t)srcs[k] * OUTC + j]);
    float t = dis[v] * acc + b2[j];
    float hh = t > 0.f ? t : (expf(t) - 1.f);
    float p = hh * Wc[j];
#pragma unroll
    for (int off = 16; off > 0; off >>= 1) p += __shfl_xor(p, off, 64);
    if (j == 0) out[v] = p + bc[0];
}

extern "C" void kernel_launch(void* const* d_in, const int* in_sizes, int n_in,
                              void* d_out, int out_size, void* d_ws, size_t ws_size,
                              hipStream_t stream) {
    const float* x  = (const float*)d_in[0];
    const int*   ei = (const int*)d_in[1];
    const float* W1 = (const float*)d_in[2];
    const float* b1 = (const float*)d_in[3];
    const float* W2 = (const float*)d_in[4];
    const float* b2 = (const float*)d_in[5];
    const float* Wc = (const float*)d_in[6];
    const float* bc = (const float*)d_in[7];
    float* out = (float*)d_out;

    const int* row = ei;            // edge_index[0] = source
    const int* col = ei + N_EDGES;  // edge_index[1] = target

    char* ws = (char*)d_ws;
    int*    deg  = (int*)   (ws + OFF_DEG);
    int*    ptr  = (int*)   (ws + OFF_PTR);
    int*    bsum = (int*)   (ws + OFF_BSUM);
    int*    gcur = (int*)   (ws + OFF_GCUR);
    float*  dis  = (float*) (ws + OFF_DIS);
    int*    srcs = (int*)   (ws + OFF_SRC);
    int*    part = (int*)   (ws + OFF_PART);
    __half* s1h  = (__half*)(ws + OFF_S1);    // aliases part (part dead before gemm1)
    float*  h1   = (float*) (ws + OFF_H1);
    __half* s2h  = (__half*)(ws + OFF_S2);

    bucket_init    <<<(NBUCK + 255) / 256, 256, 0, stream>>>(gcur);
    partition_edges<<<(N_EDGES + CHUNK - 1) / CHUNK, 256, 0, stream>>>(row, col, gcur, part);
    bucket_hist    <<<NBUCK, 256, 0, stream>>>(gcur, part, deg);
    compute_dis    <<<NB, 256, 0, stream>>>(deg, dis);
    scan_block_sums<<<NB, 256, 0, stream>>>(deg, bsum);
    scan_bsum      <<<1, 512, 0, stream>>>(bsum);
    scan_block_scan<<<NB, 256, 0, stream>>>(deg, bsum, ptr);
    bucket_fill    <<<NBUCK, 256, 0, stream>>>(gcur, part, ptr, srcs);

    gemm1  <<<(N_NODES + 63) / 64, 256, 0, stream>>>(x, W1, dis, s1h);
    gather1<<<N_NODES / 4, 256, 0, stream>>>(s1h, ptr, srcs, dis, b1, h1);
    gemm2  <<<N_NODES / 32, 256, 0, stream>>>(h1, W2, dis, s2h);
    gather2<<<N_NODES / 8, 256, 0, stream>>>(s2h, ptr, srcs, dis, b2, Wc, bc, out);
}

// Round 11
// 435.877 us; speedup vs baseline: 1.6488x; 1.0813x over previous
//
#include <hip/hip_runtime.h>
#include <hip/hip_fp16.h>
#include <math.h>

#define N_NODES 100000
#define N_EDGES 3200000
#define IN_CH   256
#define HID     64
#define OUTC    32
#define NB      ((N_NODES + 255) / 256)   // 391 scan blocks
#define NBUCK   ((N_NODES + 127) / 128)   // 782 buckets of 128 nodes (bucket = dst >> 7)
#define CHUNK   4096                      // edges per partition block
#define EPT     16                        // edges per thread (CHUNK/256)
#define CAP     4608                      // bucket capacity: mean 4092, sigma ~64 -> +8 sigma

// ---------------- workspace layout (bytes) ----------------
static constexpr size_t align256(size_t x) { return (x + 255) & ~(size_t)255; }
static constexpr size_t OFF_DEG  = 0;                                          // N ints
static constexpr size_t OFF_PTR  = OFF_DEG  + align256((size_t)N_NODES * 4);   // N ints (exclusive)
static constexpr size_t OFF_BSUM = OFF_PTR  + align256((size_t)N_NODES * 4);   // 512 ints
static constexpr size_t OFF_GCUR = OFF_BSUM + align256(512 * 4);               // NBUCK ints
static constexpr size_t OFF_DIS  = OFF_GCUR + align256((size_t)NBUCK * 4);     // N floats
static constexpr size_t OFF_SRC  = OFF_DIS  + align256((size_t)N_NODES * 4);   // E ints
static constexpr size_t OFF_PART = OFF_SRC  + align256((size_t)N_EDGES * 4);   // NBUCK*CAP ints (14.4 MB)
// s1h (N*64 halves = 12.8 MB) aliases PART (part dead after bucket_fill, before gemm1)
static constexpr size_t OFF_S1   = OFF_PART;
static constexpr size_t OFF_H1   = OFF_PART + align256((size_t)NBUCK * CAP * 4);  // N*64 floats (25.6 MB)
static constexpr size_t OFF_S2   = OFF_H1 + align256((size_t)N_NODES * HID * 4);  // N*32 halves (6.4 MB)
// total ~60 MB

// ---------------- bucket cursor init: gcur[b] = b*CAP ----------------
__global__ __launch_bounds__(256) void bucket_init(int* __restrict__ gcur) {
    int b = blockIdx.x * 256 + threadIdx.x;
    if (b < NBUCK) gcur[b] = b * CAP;
}

// ---------------- phase A: partition edges into dst-buckets (single pass) --------
// packed entry: src (17 bits) | dst_low7 << 17. Pass-1 atomicAdd returns the
// within-block rank -> saved in registers; no second histogram pass, no edge
// re-read. Reservation start hashed per block to spread gcur contention.
__global__ __launch_bounds__(256) void partition_edges(const int* __restrict__ row,
                                                       const int* __restrict__ col,
                                                       int* __restrict__ gcur,
                                                       int* __restrict__ part) {
    __shared__ int lhist[NBUCK];
    __shared__ int lbase[NBUCK];
    const int t  = threadIdx.x;
    const int e0 = blockIdx.x * CHUNK;
    for (int i = t; i < NBUCK; i += 256) lhist[i] = 0;
    __syncthreads();

    int pk[EPT], br[EPT];
#pragma unroll
    for (int i = 0; i < EPT; ++i) {
        int e = e0 + i * 256 + t;
        if (e < N_EDGES) {
            int d = col[e];
            int b = d >> 7;
            int r = atomicAdd(&lhist[b], 1);
            pk[i] = row[e] | ((d & 127) << 17);
            br[i] = b | (r << 10);           // b<1024, r<4096 -> fits
        } else {
            br[i] = -1;
        }
    }
    __syncthreads();

    const int off = (int)((blockIdx.x * 131u) % NBUCK);
    for (int i = t; i < NBUCK; i += 256) {
        int bb = i + off;
        if (bb >= NBUCK) bb -= NBUCK;
        int c = lhist[bb];
        lbase[bb] = (c > 0) ? atomicAdd(&gcur[bb], c) : 0;
    }
    __syncthreads();

#pragma unroll
    for (int i = 0; i < EPT; ++i) {
        if (br[i] >= 0) {
            int b = br[i] & 1023;
            int r = br[i] >> 10;
            part[lbase[b] + r] = pk[i];
        }
    }
}

// ---------------- phase B1: per-node degree + dis from bucket data ---------------
__global__ __launch_bounds__(256) void bucket_hist(const int* __restrict__ gcur,
                                                   const int* __restrict__ part,
                                                   int* __restrict__ deg,
                                                   float* __restrict__ dis) {
    __shared__ int lh[128];
    const int b = blockIdx.x;
    const int t = threadIdx.x;
    if (t < 128) lh[t] = 0;
    __syncthreads();
    const int cnt = gcur[b] - b * CAP;
    for (int i = t; i < cnt; i += 256)
        atomicAdd(&lh[part[(size_t)b * CAP + i] >> 17], 1);
    __syncthreads();
    int v = b * 128 + t;
    if (t < 128 && v < N_NODES) {
        int d = lh[t];
        deg[v] = d;
        dis[v] = rsqrtf((float)d + 1.0f);   // +1 self-loop
    }
}

// ---------------- 3-kernel exclusive scan of deg -> ptr ----------------
__global__ __launch_bounds__(256) void scan_block_sums(const int* __restrict__ deg,
                                                       int* __restrict__ bsum) {
    __shared__ int buf[256];
    unsigned i = blockIdx.x * 256u + threadIdx.x;
    int v = (i < N_NODES) ? deg[i] : 0;
    buf[threadIdx.x] = v;
    __syncthreads();
    for (int off = 128; off > 0; off >>= 1) {
        if (threadIdx.x < (unsigned)off) buf[threadIdx.x] += buf[threadIdx.x + off];
        __syncthreads();
    }
    if (threadIdx.x == 0) bsum[blockIdx.x] = buf[0];
}

__global__ __launch_bounds__(512) void scan_bsum(int* __restrict__ bsum) {
    __shared__ int buf[512];
    int t = threadIdx.x;
    int v = (t < NB) ? bsum[t] : 0;
    buf[t] = v;
    __syncthreads();
    for (int off = 1; off < 512; off <<= 1) {
        int add = (t >= off) ? buf[t - off] : 0;
        __syncthreads();
        buf[t] += add;
        __syncthreads();
    }
    if (t < NB) bsum[t] = buf[t] - v;  // exclusive
}

__global__ __launch_bounds__(256) void scan_block_scan(const int* __restrict__ deg,
                                                       const int* __restrict__ bsum,
                                                       int* __restrict__ ptr) {
    __shared__ int buf[256];
    unsigned i = blockIdx.x * 256u + threadIdx.x;
    int v = (i < N_NODES) ? deg[i] : 0;
    buf[threadIdx.x] = v;
    __syncthreads();
    for (int off = 1; off < 256; off <<= 1) {
        int add = (threadIdx.x >= (unsigned)off) ? buf[threadIdx.x - off] : 0;
        __syncthreads();
        buf[threadIdx.x] += add;
        __syncthreads();
    }
    if (i < N_NODES) ptr[i] = bsum[blockIdx.x] + buf[threadIdx.x] - v;  // exclusive
}

// ---------------- phase B2: fill srcs; writes confined to ~16KB window/block -------
__global__ __launch_bounds__(256) void bucket_fill(const int* __restrict__ gcur,
                                                   const int* __restrict__ part,
                                                   const int* __restrict__ ptr,
                                                   int* __restrict__ srcs) {
    __shared__ int lcur[128];
    const int b = blockIdx.x;
    const int t = threadIdx.x;
    if (t < 128) lcur[t] = 0;
    __syncthreads();
    const int cnt = gcur[b] - b * CAP;
    for (int i = t; i < cnt; i += 256) {
        int p    = part[(size_t)b * CAP + i];
        int dlow = p >> 17;
        int src  = p & 0x1FFFF;
        int r    = atomicAdd(&lcur[dlow], 1);        // LDS cursor
        srcs[ptr[b * 128 + dlow] + r] = src;
    }
}

// ---------------- GEMM1: s1h[n][j] = fp16(dis[n] * (x[n,:] @ W1[:,j])) ----------
// Both operands staged in LDS (r10 structure, unchanged).
__global__ __launch_bounds__(256) void gemm1(const float* __restrict__ x,
                                             const float* __restrict__ W1,
                                             const float* __restrict__ dis,
                                             __half* __restrict__ s1h) {
    __shared__ float wlds[64 * HID];   // 16 KB k-chunk of W1: [k_local][j]
    __shared__ float xlds[64 * 68];    // 17 KB x-tile: [row_local][k_local], stride 68

    const int t  = threadIdx.x;
    const int tx = t & 15;
    const int ty = t >> 4;
    const int row0 = blockIdx.x * 64;

    float acc[4][4] = {{0.f}};

    for (int kt = 0; kt < IN_CH / 64; ++kt) {
        {
            const float4* w4 = (const float4*)(W1 + (size_t)kt * 64 * HID);
            float4* l4 = (float4*)wlds;
#pragma unroll
            for (int i = 0; i < 4; ++i) l4[i * 256 + t] = w4[i * 256 + t];
        }
        {
#pragma unroll
            for (int i = 0; i < 4; ++i) {
                int L  = i * 256 + t;
                int rl = L >> 4;
                int k4 = L & 15;
                int rg = row0 + rl;
                float4 v;
                if (rg < N_NODES) v = ((const float4*)x)[(size_t)rg * 64 + kt * 16 + k4];
                else              v = make_float4(0.f, 0.f, 0.f, 0.f);
                *(float4*)(&xlds[rl * 68 + k4 * 4]) = v;
            }
        }
        __syncthreads();

        const float4* wl4 = (const float4*)wlds;
#pragma unroll 4
        for (int k4 = 0; k4 < 16; ++k4) {
            float4 xv[4];
#pragma unroll
            for (int i = 0; i < 4; ++i)
                xv[i] = *(const float4*)(&xlds[(ty * 4 + i) * 68 + k4 * 4]);
#pragma unroll
            for (int kk = 0; kk < 4; ++kk) {
                float4 bv = wl4[(k4 * 4 + kk) * 16 + tx];
#pragma unroll
                for (int i = 0; i < 4; ++i) {
                    const float* xf = (const float*)&xv[i];
                    float a = xf[kk];
                    acc[i][0] += a * bv.x;
                    acc[i][1] += a * bv.y;
                    acc[i][2] += a * bv.z;
                    acc[i][3] += a * bv.w;
                }
            }
        }
        __syncthreads();
    }

#pragma unroll
    for (int i = 0; i < 4; ++i) {
        int rr = row0 + ty * 4 + i;
        if (rr < N_NODES) {
            float d = dis[rr];
            __half2 p0 = __floats2half2_rn(acc[i][0] * d, acc[i][1] * d);
            __half2 p1 = __floats2half2_rn(acc[i][2] * d, acc[i][3] * d);
            __half2* dst = (__half2*)(s1h + (size_t)rr * HID + tx * 4);
            dst[0] = p0;
            dst[1] = p1;
        }
    }
}

// ---------------- gather layer 1 + ELU: h1 fp32 from fp16 s1 ----------------
__global__ __launch_bounds__(256) void gather1(const __half* __restrict__ s1h,
                                               const int* __restrict__ ptr,
                                               const int* __restrict__ srcs,
                                               const float* __restrict__ dis,
                                               const float* __restrict__ b1,
                                               float* __restrict__ h1) {
    const int j = threadIdx.x & 63;
    const int v = __builtin_amdgcn_readfirstlane(blockIdx.x * 4 + (threadIdx.x >> 6));
    float acc = __half2float(s1h[(size_t)v * HID + j]);   // self-loop term
    const int beg = ptr[v];
    const int end = (v + 1 < N_NODES) ? ptr[v + 1] : N_EDGES;
    int k = beg;
    for (; k + 8 <= end; k += 8) {
        int u0 = srcs[k],     u1 = srcs[k + 1], u2 = srcs[k + 2], u3 = srcs[k + 3];
        int u4 = srcs[k + 4], u5 = srcs[k + 5], u6 = srcs[k + 6], u7 = srcs[k + 7];
        float f0 = __half2float(s1h[(size_t)u0 * HID + j]);
        float f1 = __half2float(s1h[(size_t)u1 * HID + j]);
        float f2 = __half2float(s1h[(size_t)u2 * HID + j]);
        float f3 = __half2float(s1h[(size_t)u3 * HID + j]);
        float f4 = __half2float(s1h[(size_t)u4 * HID + j]);
        float f5 = __half2float(s1h[(size_t)u5 * HID + j]);
        float f6 = __half2float(s1h[(size_t)u6 * HID + j]);
        float f7 = __half2float(s1h[(size_t)u7 * HID + j]);
        acc += ((f0 + f1) + (f2 + f3)) + ((f4 + f5) + (f6 + f7));
    }
    for (; k < end; ++k) acc += __half2float(s1h[(size_t)srcs[k] * HID + j]);
    float tt = dis[v] * acc + b1[j];
    h1[(size_t)v * HID + j] = tt > 0.f ? tt : (expf(tt) - 1.f);
}

// ---------------- GEMM2: s2h[n][j] = fp16(dis[n] * (h1[n,:] @ W2[:,j])) --------
__global__ __launch_bounds__(256) void gemm2(const float* __restrict__ h,
                                             const float* __restrict__ W2,
                                             const float* __restrict__ dis,
                                             __half* __restrict__ s2h) {
    const int j  = threadIdx.x & 31;
    const int g  = threadIdx.x >> 5;
    const int n0 = blockIdx.x * 32 + g * 4;
    const float* h0 = h + (size_t)n0 * HID;
    float a0 = 0.f, a1 = 0.f, a2 = 0.f, a3 = 0.f;
#pragma unroll 4
    for (int k = 0; k < HID; ++k) {
        float w = W2[k * OUTC + j];
        a0 += h0[k] * w;
        a1 += h0[HID + k] * w;
        a2 += h0[2 * HID + k] * w;
        a3 += h0[3 * HID + k] * w;
    }
    size_t o = (size_t)n0 * OUTC + j;
    s2h[o]            = __float2half(dis[n0]     * a0);
    s2h[o + OUTC]     = __float2half(dis[n0 + 1] * a1);
    s2h[o + 2 * OUTC] = __float2half(dis[n0 + 2] * a2);
    s2h[o + 3 * OUTC] = __float2half(dis[n0 + 3] * a3);
}

// ---------------- gather layer 2 + ELU + final projection ----------------
__global__ __launch_bounds__(256) void gather2(const __half* __restrict__ s2h,
                                               const int* __restrict__ ptr,
                                               const int* __restrict__ srcs,
                                               const float* __restrict__ dis,
                                               const float* __restrict__ b2,
                                               const float* __restrict__ Wc,
                                               const float* __restrict__ bc,
                                               float* __restrict__ out) {
    const int j = threadIdx.x & 31;
    const int v = blockIdx.x * 8 + (threadIdx.x >> 5);
    float acc = __half2float(s2h[(size_t)v * OUTC + j]);  // self-loop term
    const int beg = ptr[v];
    const int end = (v + 1 < N_NODES) ? ptr[v + 1] : N_EDGES;
    int k = beg;
    for (; k + 8 <= end; k += 8) {
        int u0 = srcs[k],     u1 = srcs[k + 1], u2 = srcs[k + 2], u3 = srcs[k + 3];
        int u4 = srcs[k + 4], u5 = srcs[k + 5], u6 = srcs[k + 6], u7 = srcs[k + 7];
        float f0 = __half2float(s2h[(size_t)u0 * OUTC + j]);
        float f1 = __half2float(s2h[(size_t)u1 * OUTC + j]);
        float f2 = __half2float(s2h[(size_t)u2 * OUTC + j]);
        float f3 = __half2float(s2h[(size_t)u3 * OUTC + j]);
        float f4 = __half2float(s2h[(size_t)u4 * OUTC + j]);
        float f5 = __half2float(s2h[(size_t)u5 * OUTC + j]);
        float f6 = __half2float(s2h[(size_t)u6 * OUTC + j]);
        float f7 = __half2float(s2h[(size_t)u7 * OUTC + j]);
        acc += ((f0 + f1) + (f2 + f3)) + ((f4 + f5) + (f6 + f7));
    }
    for (; k < end; ++k) acc += __half2float(s2h[(size_t)srcs[k] * OUTC + j]);
    float t = dis[v] * acc + b2[j];
    float hh = t > 0.f ? t : (expf(t) - 1.f);
    float p = hh * Wc[j];
#pragma unroll
    for (int off = 16; off > 0; off >>= 1) p += __shfl_xor(p, off, 64);
    if (j == 0) out[v] = p + bc[0];
}

extern "C" void kernel_launch(void* const* d_in, const int* in_sizes, int n_in,
                              void* d_out, int out_size, void* d_ws, size_t ws_size,
                              hipStream_t stream) {
    const float* x  = (const float*)d_in[0];
    const int*   ei = (const int*)d_in[1];
    const float* W1 = (const float*)d_in[2];
    const float* b1 = (const float*)d_in[3];
    const float* W2 = (const float*)d_in[4];
    const float* b2 = (const float*)d_in[5];
    const float* Wc = (const float*)d_in[6];
    const float* bc = (const float*)d_in[7];
    float* out = (float*)d_out;

    const int* row = ei;            // edge_index[0] = source
    const int* col = ei + N_EDGES;  // edge_index[1] = target

    char* ws = (char*)d_ws;
    int*    deg  = (int*)   (ws + OFF_DEG);
    int*    ptr  = (int*)   (ws + OFF_PTR);
    int*    bsum = (int*)   (ws + OFF_BSUM);
    int*    gcur = (int*)   (ws + OFF_GCUR);
    float*  dis  = (float*) (ws + OFF_DIS);
    int*    srcs = (int*)   (ws + OFF_SRC);
    int*    part = (int*)   (ws + OFF_PART);
    __half* s1h  = (__half*)(ws + OFF_S1);    // aliases part (part dead before gemm1)
    float*  h1   = (float*) (ws + OFF_H1);
    __half* s2h  = (__half*)(ws + OFF_S2);

    bucket_init    <<<(NBUCK + 255) / 256, 256, 0, stream>>>(gcur);
    partition_edges<<<(N_EDGES + CHUNK - 1) / CHUNK, 256, 0, stream>>>(row, col, gcur, part);
    bucket_hist    <<<NBUCK, 256, 0, stream>>>(gcur, part, deg, dis);
    scan_block_sums<<<NB, 256, 0, stream>>>(deg, bsum);
    scan_bsum      <<<1, 512, 0, stream>>>(bsum);
    scan_block_scan<<<NB, 256, 0, stream>>>(deg, bsum, ptr);
    bucket_fill    <<<NBUCK, 256, 0, stream>>>(gcur, part, ptr, srcs);

    gemm1  <<<(N_NODES + 63) / 64, 256, 0, stream>>>(x, W1, dis, s1h);
    gather1<<<N_NODES / 4, 256, 0, stream>>>(s1h, ptr, srcs, dis, b1, h1);
    gemm2  <<<N_NODES / 32, 256, 0, stream>>>(h1, W2, dis, s2h);
    gather2<<<N_NODES / 8, 256, 0, stream>>>(s2h, ptr, srcs, dis, b2, Wc, bc, out);
}